// Round 18
// baseline (6600.558 us; speedup 1.0000x reference)
//
#include <hip/hip_runtime.h>
#include <hip/hip_bf16.h>

// ---------- types ----------
typedef short    bf16x8 __attribute__((ext_vector_type(8)));   // 8 bf16 (4 VGPRs), MFMA A/B frag
typedef float    f32x4  __attribute__((ext_vector_type(4)));   // MFMA C/D frag
typedef unsigned short u16x8 __attribute__((ext_vector_type(8)));

#define B_  64
#define S_  128
#define T_  128
#define E_  1024
#define H_  1024
#define NBLK 256

#define RLX __ATOMIC_RELAXED
#define AGT __HIP_MEMORY_SCOPE_AGENT

__device__ __forceinline__ unsigned short f2bf(float f) {
    unsigned u = __float_as_uint(f);
    unsigned r = (u + 0x7FFFu + ((u >> 16) & 1u)) >> 16;   // RNE
    return (unsigned short)r;
}
__device__ __forceinline__ float bf2f(unsigned short u) {
    return __uint_as_float((unsigned)u << 16);
}
__device__ __forceinline__ float my_tanh(float x) {
    float e = __expf(2.0f * x);
    return 1.0f - 2.0f / (e + 1.0f);
}
__device__ __forceinline__ float my_sig(float x) {
    return 1.0f / (1.0f + __expf(-x));
}

// ---------- coherent (L2-bypass) relaxed accessors ----------
__device__ __forceinline__ void st8c(void* p, unsigned long long v) {
    __hip_atomic_store((unsigned long long*)p, v, RLX, AGT);
}
__device__ __forceinline__ unsigned long long ld8c(const void* p) {
    return __hip_atomic_load((const unsigned long long*)p, RLX, AGT);
}
__device__ __forceinline__ void st4c(void* p, unsigned v) {
    __hip_atomic_store((unsigned*)p, v, RLX, AGT);
}
__device__ __forceinline__ void st4f(void* p, float v) {
    __hip_atomic_store((float*)p, v, RLX, AGT);
}
__device__ __forceinline__ float ld4f(const void* p) {
    return __hip_atomic_load((const float*)p, RLX, AGT);
}

// ---------- async global->LDS (16B per lane; LDS dest = wave base + lane*16) ----------
__device__ __forceinline__ void gld_lds16(const void* g, void* l) {
    __builtin_amdgcn_global_load_lds(
        (const __attribute__((address_space(1))) unsigned int*)(unsigned long long)g,
        (__attribute__((address_space(3))) unsigned int*)(unsigned int)(unsigned long long)l,
        16, 0, 0);
}

// ---------- 2-level grid barrier: 32 leaves x 8, relaxed atomics only ----------
__device__ __forceinline__ void gbar(int* sync, int g, int ord) {
    __syncthreads();                         // drains vmcnt -> sc1 stores at coherence point
    if (threadIdx.x == 0) {
        int* lc = sync + 64 + (g >> 3) * 64;
        int* lg = lc + 32;
        if (__hip_atomic_fetch_add(lc, 1, RLX, AGT) == 8 * ord - 1) {
            if (__hip_atomic_fetch_add(sync, 1, RLX, AGT) == 32 * ord - 1) {
                __hip_atomic_store(sync + 32, ord, RLX, AGT);
            } else {
                while (__hip_atomic_load(sync + 32, RLX, AGT) < ord)
                    __builtin_amdgcn_s_sleep(2);
            }
            __hip_atomic_store(lg, ord, RLX, AGT);
        } else {
            while (__hip_atomic_load(lg, RLX, AGT) < ord)
                __builtin_amdgcn_s_sleep(2);
        }
    }
    __syncthreads();
}

// ---------- f32 -> bf16 conversion ----------
__global__ void k_cvt(const float* __restrict__ s, unsigned short* __restrict__ d, long n) {
    long i = ((long)blockIdx.x * blockDim.x + threadIdx.x) * 4;
    if (i >= n) return;
    float4 f = *(const float4*)(s + i);
    ushort4 o;
    o.x = f2bf(f.x); o.y = f2bf(f.y); o.z = f2bf(f.z); o.w = f2bf(f.w);
    *(ushort4*)(d + i) = o;
}

// trg_embed (B,T,1024) -> preC[(b*T+t)*4096 + 0..1023]
__global__ void k_cvt_te(const float* __restrict__ s, unsigned short* __restrict__ d, long n) {
    long i = ((long)blockIdx.x * blockDim.x + threadIdx.x) * 4;
    if (i >= n) return;
    float4 f = *(const float4*)(s + i);
    long row = i >> 10, col = i & 1023;
    ushort4 o;
    o.x = f2bf(f.x); o.y = f2bf(f.y); o.z = f2bf(f.z); o.w = f2bf(f.w);
    *(ushort4*)(d + row * 4096 + col) = o;
}

// ---------- small MFMA GEMM (h0 only): C[M,N] = A[M,K] @ W[N,K]^T ----------
template<int OUTBF>
__global__ __launch_bounds__(256) void k_gemm(const unsigned short* __restrict__ A, long lda,
                                              const unsigned short* __restrict__ W, long ldw,
                                              void* __restrict__ Cv, long ldc, int K) {
    const int lane = threadIdx.x & 63;
    const int wv   = threadIdx.x >> 6;
    const int r    = lane & 15, g = lane >> 4;
    const long m0  = (long)blockIdx.y * 64 + wv * 16;
    const long n0  = (long)blockIdx.x * 64;
    const unsigned short* a  = A + (m0 + r) * lda + g * 8;
    const unsigned short* w0 = W + (n0 + r) * ldw + g * 8;
    f32x4 acc[4] = {};
    for (int k = 0; k < K; k += 32) {
        bf16x8 av = *(const bf16x8*)(a + k);
#pragma unroll
        for (int j = 0; j < 4; ++j) {
            bf16x8 bv = *(const bf16x8*)(w0 + (long)j * 16 * ldw + k);
            acc[j] = __builtin_amdgcn_mfma_f32_16x16x32_bf16(av, bv, acc[j], 0, 0, 0);
        }
    }
#pragma unroll
    for (int j = 0; j < 4; ++j) {
        long row = m0 + g * 4;
        long col = n0 + j * 16 + r;
#pragma unroll
        for (int rr = 0; rr < 4; ++rr) {
            float v = acc[j][rr];
            if (OUTBF) ((unsigned short*)Cv)[(row + rr) * ldc + col] = f2bf(v);
            else       ((float*)Cv)[(row + rr) * ldc + col] = v;
        }
    }
}

// ---------- m97-style 128x128 GEMM: global_load_lds staging, 4 waves (2x2), BK=32 ----------
template<int OUTBF>
__global__ __launch_bounds__(256) void k_gemm128(const unsigned short* __restrict__ A, long lda,
                                                 const unsigned short* __restrict__ W, long ldw,
                                                 void* __restrict__ Cv, long ldc, int K) {
    __shared__ unsigned short lA[128 * 32];
    __shared__ unsigned short lB[128 * 32];
    const int tid  = threadIdx.x;
    const int lane = tid & 63, wv = tid >> 6;
    const int r = lane & 15, gg = lane >> 4;
    const int wm = (wv >> 1) * 64, wn = (wv & 1) * 64;
    const long m0 = (long)blockIdx.y * 128;
    const long n0 = (long)blockIdx.x * 128;
    const int c0 = 2 * wv, c1 = 2 * wv + 1;
    const int ra0 = c0 * 16 + (lane >> 2);
    const int ra1 = c1 * 16 + (lane >> 2);
    const int cb8 = (lane & 3) * 8;
    const unsigned short* a0 = A + (m0 + ra0) * lda + cb8;
    const unsigned short* a1 = A + (m0 + ra1) * lda + cb8;
    const unsigned short* b0 = W + (n0 + ra0) * ldw + cb8;
    const unsigned short* b1 = W + (n0 + ra1) * ldw + cb8;
    f32x4 acc[4][4] = {};
    for (int k0 = 0; k0 < K; k0 += 32) {
        __syncthreads();
        gld_lds16(a0 + k0, &lA[c0 * 512]);
        gld_lds16(a1 + k0, &lA[c1 * 512]);
        gld_lds16(b0 + k0, &lB[c0 * 512]);
        gld_lds16(b1 + k0, &lB[c1 * 512]);
        __syncthreads();
        bf16x8 av[4], bv[4];
#pragma unroll
        for (int i = 0; i < 4; ++i) {
            av[i] = *(const bf16x8*)&lA[(wm + i * 16 + r) * 32 + gg * 8];
            bv[i] = *(const bf16x8*)&lB[(wn + i * 16 + r) * 32 + gg * 8];
        }
#pragma unroll
        for (int mi = 0; mi < 4; ++mi)
#pragma unroll
            for (int ni = 0; ni < 4; ++ni)
                acc[mi][ni] = __builtin_amdgcn_mfma_f32_16x16x32_bf16(av[mi], bv[ni], acc[mi][ni], 0, 0, 0);
    }
#pragma unroll
    for (int mi = 0; mi < 4; ++mi) {
#pragma unroll
        for (int ni = 0; ni < 4; ++ni) {
            const long col = n0 + wn + ni * 16 + r;
#pragma unroll
            for (int rr = 0; rr < 4; ++rr) {
                const long row = m0 + wm + mi * 16 + gg * 4 + rr;
                float v = acc[mi][ni][rr];
                if (OUTBF) ((unsigned short*)Cv)[row * ldc + col] = f2bf(v);
                else       ((float*)Cv)[row * ldc + col] = v;
            }
        }
    }
}

// ---------- h0 activation ----------
__global__ void k_h0act(const float* __restrict__ hp, const float* __restrict__ bb,
                        float* __restrict__ h, unsigned short* __restrict__ hbf) {
    int i = blockIdx.x * 256 + threadIdx.x;   // 65536
    float v = my_tanh(hp[i] + bb[i & 1023]);
    h[i] = v; hbf[i] = f2bf(v);
}

// ---------- persistent step loop: 256 blocks x 1024 thr, 2 gbars + 1 minibar/step ----------
// P2': per-block q-slice (broadcast-A MFMA, XCD-pinned 512KB Wq slice) + energy partials
//      over h-quarter (separable!) -> scb exchange -> softmax -> ctx from LDS-pinned eh.
// P3': gi (wv<12) + gh (wv 12-14, Whh j-slices XCD-pinned) + GRU gates.
__global__ __launch_bounds__(1024) void k_steps(
        const unsigned short* __restrict__ pk, const unsigned short* __restrict__ eh,
        const unsigned short* __restrict__ whp, const unsigned short* __restrict__ wih,
        const float* __restrict__ We, const float* __restrict__ gix,
        const float* __restrict__ bih, const float* __restrict__ bhh,
        const float* __restrict__ h0f, const unsigned short* __restrict__ hbf,
        unsigned short* __restrict__ preC,
        float* __restrict__ o_states, float* __restrict__ o_hf,
        int* __restrict__ sync, float* __restrict__ scb) {
    __shared__ unsigned short ehs[S_ * 512];  // 128 KB: eh[p2_b][:, hq*512 .. +512) resident
    __shared__ float smf[16 * 64 * 4];        // 16 KB, reused per phase
    __shared__ float qs[256];                 // q slice [hq*256, +256)
    __shared__ unsigned short hsm[256];
    const int g    = blockIdx.x;
    const int tid  = threadIdx.x;
    const int wv   = tid >> 6, lane = tid & 63;
    const int r    = lane & 15, gg = lane >> 4;

    // ---- P2 roles: XCD (g&7) pins h-quarter hq (= g&3) and Wq/pk slices ----
    const int p2_hq = g & 3;
    const int p2_b  = ((g >> 2) & 1) + 2 * (g >> 3);      // bijective; 32 batches per XCD
    // ---- P3 roles: XCD (g&7) pins the wih j-slice; batch-group from high bits ----
    const int bg = g >> 6;                                // batch-group 0..3
    const int jt = (g & 7) * 8 + ((g >> 3) & 7);          // j-tile 0..63 (8 per XCD)
    const int j0 = jt * 16, b0 = bg * 16;
    const int lr = tid >> 4, lc = tid & 15;
    float hreg = (tid < 256) ? h0f[(long)(b0 + lr) * 1024 + j0 + lc] : 0.f;

    // hoist We slice (invariant): lane covers h = hq*256 + lane*4 .. +3
    const float we0 = We[p2_hq * 256 + lane * 4];
    const float we1 = We[p2_hq * 256 + lane * 4 + 1];
    const float we2 = We[p2_hq * 256 + lane * 4 + 2];
    const float we3 = We[p2_hq * 256 + lane * 4 + 3];

    // ---- one-time: stage this block's eh slice into LDS (128 rows x 512 cols bf16) ----
    {
        const unsigned short* src = eh + (long)p2_b * S_ * 2048 + p2_hq * 512;
#pragma unroll
        for (int it = 0; it < 8; ++it) {
            int i = it * 1024 + tid;              // 8192 chunks of 8 ushorts
            int row = i >> 6, c8i = (i & 63) * 8;
            *(u16x8*)&ehs[row * 512 + c8i] = *(const u16x8*)(src + (long)row * 2048 + c8i);
        }
    }
    __syncthreads();

    int ord = 0;

#pragma unroll 1
    for (int t = 0; t < T_; ++t) {
        // ======== P2': q-slice + energy partials + softmax + ctx ========
        {
            const int b = p2_b, hq = p2_hq;
            const unsigned short* hsrc = (t == 0)
                ? hbf + (long)b * 1024
                : preC + ((long)b * T_ + (t - 1)) * 4096 + 1024;   // plain, per-step-unique
            // --- q slice: wave wv -> cols hq*256 + wv*16 .. +16 (broadcast-A MFMA) ---
            {
                const int n0 = hq * 256 + wv * 16;
                f32x4 qa = {};
                for (int k = 0; k < 1024; k += 32) {
                    bf16x8 av = *(const bf16x8*)(hsrc + k + gg * 8);   // same for all rows
                    bf16x8 bv = *(const bf16x8*)(whp + (long)(n0 + r) * 1024 + k + gg * 8);
                    qa = __builtin_amdgcn_mfma_f32_16x16x32_bf16(av, bv, qa, 0, 0, 0);
                }
                if (gg == 0) qs[wv * 16 + r] = qa[0];   // all C rows identical; row 0
            }
            __syncthreads();
            // --- energy partials over h-slice: wave wv -> scores wv*8..+8; lane: 4 dims ---
            const float q0 = qs[lane * 4], q1 = qs[lane * 4 + 1];
            const float q2 = qs[lane * 4 + 2], q3 = qs[lane * 4 + 3];
            const unsigned short* pkb = pk + ((long)b * S_ + wv * 8) * 1024 + hq * 256 + lane * 4;
#pragma unroll 2
            for (int ss = 0; ss < 8; ++ss) {
                ushort4 pv = *(const ushort4*)(pkb + (long)ss * 1024);
                float acc = my_tanh(q0 + bf2f(pv.x)) * we0
                          + my_tanh(q1 + bf2f(pv.y)) * we1
                          + my_tanh(q2 + bf2f(pv.z)) * we2
                          + my_tanh(q3 + bf2f(pv.w)) * we3;
#pragma unroll
                for (int off = 32; off; off >>= 1) acc += __shfl_xor(acc, off);
                if (lane == 0) st4f(&scb[b * 512 + (wv * 8 + ss) * 4 + hq], acc);
            }
            // --- 4-block mini-barrier (per-batch monotonic counter) ---
            __syncthreads();                 // drains vmcnt: partial stores at coherence point
            if (tid == 0) {
                int* bc = sync + 4096 + b * 32;
                __hip_atomic_fetch_add(bc, 1, RLX, AGT);
                while (__hip_atomic_load(bc, RLX, AGT) < 4 * (t + 1))
                    __builtin_amdgcn_s_sleep(2);
            }
            __syncthreads();
            // --- softmax over 128 (threads 0..127): sum 4 quarter-partials ---
            float* red = &smf[648];
            float e = 0.f, sc = 0.f;
            if (tid < 128) {
                sc = ld4f(&scb[b * 512 + tid * 4])     + ld4f(&scb[b * 512 + tid * 4 + 1])
                   + ld4f(&scb[b * 512 + tid * 4 + 2]) + ld4f(&scb[b * 512 + tid * 4 + 3]);
                float m = sc;
#pragma unroll
                for (int off = 32; off; off >>= 1) m = fmaxf(m, __shfl_xor(m, off));
                if ((tid & 63) == 0) red[tid >> 6] = m;
            }
            __syncthreads();
            if (tid < 128) {
                float M = fmaxf(red[0], red[1]);
                e = __expf(sc - M);
                float s = e;
#pragma unroll
                for (int off = 32; off; off >>= 1) s += __shfl_xor(s, off);
                if ((tid & 63) == 0) red[2 + (tid >> 6)] = s;
            }
            __syncthreads();
            if (tid < 128) smf[512 + tid] = e / (red[2] + red[3]);
            __syncthreads();
            // --- context: thread = (col-pair cp, s-segment sseg of 32); LDS source ---
            const int cp = tid & 255, sseg = tid >> 8;
            const unsigned short* ehp = ehs + (sseg * 32) * 512 + cp * 2;
            float a0 = 0.f, a1 = 0.f;
#pragma unroll 4
            for (int s2 = 0; s2 < 32; ++s2) {
                float alv = smf[512 + sseg * 32 + s2];
                ushort2 v = *(const ushort2*)(ehp + s2 * 512);
                a0 += alv * bf2f(v.x); a1 += alv * bf2f(v.y);
            }
            smf[1024 + (sseg * 256 + cp) * 2]     = a0;
            smf[1024 + (sseg * 256 + cp) * 2 + 1] = a1;
            __syncthreads();
            if (tid < 256) {
                float b0s = smf[1024 + tid * 2]         + smf[1024 + (256 + tid) * 2]
                          + smf[1024 + (512 + tid) * 2] + smf[1024 + (768 + tid) * 2];
                float b1s = smf[1024 + tid * 2 + 1]         + smf[1024 + (256 + tid) * 2 + 1]
                          + smf[1024 + (512 + tid) * 2 + 1] + smf[1024 + (768 + tid) * 2 + 1];
                unsigned pack = (unsigned)f2bf(b0s) | ((unsigned)f2bf(b1s) << 16);
                st4c(preC + ((long)b * T_ + t) * 4096 + 2048 + hq * 512 + tid * 2, pack);
            }
        }
        gbar(sync, g, ++ord);

        // ======== P3': gi_ctx (wv<12) + gh (wv 12-14, K=1024) MFMA + GRU gates ========
        {
            if (wv < 12) {
                const int c = wv >> 2, ks = wv & 3, k0 = ks * 512;
                const unsigned short* ar = preC + ((long)(b0 + r) * T_ + t) * 4096 + 2048 + k0 + gg * 8; // plain
                const unsigned short* bw = wih + ((long)(c * 1024 + j0 + r)) * 3072 + 1024 + k0 + gg * 8;
                f32x4 acc = {};
#pragma unroll
                for (int k = 0; k < 512; k += 32) {
                    bf16x8 av = *(const bf16x8*)(ar + k);
                    bf16x8 bv = *(const bf16x8*)(bw + k);
                    acc = __builtin_amdgcn_mfma_f32_16x16x32_bf16(av, bv, acc, 0, 0, 0);
                }
                *(f32x4*)&smf[(wv * 64 + lane) * 4] = acc;
            } else if (wv < 15) {
                // gh chunk c = wv-12: gh = h_prev @ Whh[c]^T, K=1024 (Whh rows at whp+1024)
                const int c = wv - 12;
                const unsigned short* ar = (t == 0)
                    ? hbf + (long)(b0 + r) * 1024 + gg * 8
                    : preC + ((long)(b0 + r) * T_ + (t - 1)) * 4096 + 1024 + gg * 8;   // plain
                const unsigned short* bw = whp + (long)(1024 + c * 1024 + j0 + r) * 1024 + gg * 8;
                f32x4 acc = {};
#pragma unroll 4
                for (int k = 0; k < 1024; k += 32) {
                    bf16x8 av = *(const bf16x8*)(ar + k);
                    bf16x8 bv = *(const bf16x8*)(bw + k);
                    acc = __builtin_amdgcn_mfma_f32_16x16x32_bf16(av, bv, acc, 0, 0, 0);
                }
                *(f32x4*)&smf[(wv * 64 + lane) * 4] = acc;
            }
            __syncthreads();
            if (tid < 256) {
                const int lane_ = (lr >> 2) * 16 + lc, rr_ = lr & 3;
                float gi[3], gh[3];
#pragma unroll
                for (int c = 0; c < 3; ++c) {
                    gi[c] = smf[((c * 4 + 0) * 64 + lane_) * 4 + rr_]
                          + smf[((c * 4 + 1) * 64 + lane_) * 4 + rr_]
                          + smf[((c * 4 + 2) * 64 + lane_) * 4 + rr_]
                          + smf[((c * 4 + 3) * 64 + lane_) * 4 + rr_];
                    gh[c] = smf[((12 + c) * 64 + lane_) * 4 + rr_];
                }
                const int b = b0 + lr, j = j0 + lc;
                const long bt = (long)b * T_ + t;
                float grv = gix[bt * 3072 + j]        + gi[0] + bih[j]        + gh[0] + bhh[j];
                float gzv = gix[bt * 3072 + 1024 + j] + gi[1] + bih[1024 + j] + gh[1] + bhh[1024 + j];
                float gni = gix[bt * 3072 + 2048 + j] + gi[2] + bih[2048 + j];
                float ghn2 = gh[2] + bhh[2048 + j];
                float rg = my_sig(grv);
                float zg = my_sig(gzv);
                float nv = my_tanh(gni + rg * ghn2);
                float hn = (1.f - zg) * nv + zg * hreg;
                hreg = hn;
                unsigned short hb16 = f2bf(hn);
                o_states[bt * 1024 + j] = hn;                    // plain (read after kernel)
                if (t == T_ - 1) o_hf[(long)b * 1024 + j] = hn;  // plain
                hsm[tid] = hb16;
            }
            __syncthreads();
            // pack h_t -> preC h-slot (sc1; next-step P2'/P3'-gh read plain)
            if (tid < 64) {
                const int plr = tid >> 2, pc4 = (tid & 3) * 4;
                unsigned long long v =
                      (unsigned long long)hsm[plr * 16 + pc4]
                    | ((unsigned long long)hsm[plr * 16 + pc4 + 1] << 16)
                    | ((unsigned long long)hsm[plr * 16 + pc4 + 2] << 32)
                    | ((unsigned long long)hsm[plr * 16 + pc4 + 3] << 48);
                st8c(preC + ((long)(b0 + plr) * T_ + t) * 4096 + 1024 + j0 + pc4, v);
            }
        }
        gbar(sync, g, ++ord);
    }
}

// ---------- host ----------
extern "C" void kernel_launch(void* const* d_in, const int* in_sizes, int n_in,
                              void* d_out, int out_size, void* d_ws, size_t ws_size,
                              hipStream_t stream) {
    const float* te  = (const float*)d_in[0];
    const float* eh  = (const float*)d_in[1];
    const float* ef  = (const float*)d_in[2];
    const float* Wb  = (const float*)d_in[5];
    const float* bb  = (const float*)d_in[6];
    const float* Wk  = (const float*)d_in[7];
    const float* Wq  = (const float*)d_in[8];
    const float* We  = (const float*)d_in[9];
    const float* Wih = (const float*)d_in[10];
    const float* Whh = (const float*)d_in[11];
    const float* bih = (const float*)d_in[12];
    const float* bhh = (const float*)d_in[13];
    const float* Wpre= (const float*)d_in[14];

    char* ws = (char*)d_ws;
    if (ws_size < 272236544UL) return;   // loud failure (output stays poisoned)
    float*          h0f   = (float*)(ws + 0);                  // 64*1024*4
    float*          hp    = (float*)(ws + 262144);             // 64*4096*4 (h0 scratch)
    unsigned short* hbf   = (unsigned short*)(ws + 1310720);   // 64*1024*2 (h0 only)
    unsigned short* efb   = (unsigned short*)(ws + 1441792);   // 64*2048*2 (init only)
    int*            syncb = (int*)(ws + 1441792 + 65536);      // barrier vars + batch counters
    float*          scb   = (float*)(ws + 1572864);            // 64*512*4 partial-score exchange
    unsigned short* ehb   = (unsigned short*)(ws + 1703936);   // B*S*2048*2
    unsigned short* pkb   = (unsigned short*)(ws + 35258368);  // B*S*1024*2
    unsigned short* preC  = (unsigned short*)(ws + 52035584);  // B*T*4096*2
    float*          gix   = (float*)(ws + 119144448);          // B*T*3072*4
    unsigned short* wbb   = (unsigned short*)(ws + 219807744); // 1024*2048*2
    unsigned short* wkb   = (unsigned short*)(ws + 224002048); // 1024*2048*2
    unsigned short* whpb  = (unsigned short*)(ws + 228196352); // 4096*1024*2  [Wq; Whh]
    unsigned short* wihb  = (unsigned short*)(ws + 236584960); // 3072*3072*2
    unsigned short* wpreb = (unsigned short*)(ws + 255459328); // 2048*4096*2

    float* o_states = (float*)d_out;                 // (B,T,H)
    float* o_hf     = o_states + (long)B_ * T_ * H_; // (1,B,H)
    float* o_pre    = o_hf + (long)B_ * H_;          // (B,T,2H)

    auto cvt = [&](const float* s, unsigned short* d, long n) {
        k_cvt<<<dim3((unsigned)((n / 4 + 255) / 256)), 256, 0, stream>>>(s, d, n);
    };
    cvt(eh,  ehb,  (long)B_ * S_ * 2048);
    cvt(ef,  efb,  (long)B_ * 2048);
    cvt(Wb,  wbb,  1024L * 2048);
    cvt(Wk,  wkb,  1024L * 2048);
    cvt(Wq,  whpb, 1024L * 1024);
    cvt(Whh, whpb + 1024L * 1024, 3072L * 1024);
    cvt(Wih, wihb, 3072L * 3072);
    cvt(Wpre,wpreb,2048L * 4096);
    k_cvt_te<<<8192, 256, 0, stream>>>(te, preC, (long)B_ * T_ * 1024);

    // h0 = tanh(encoder_final @ W_bridge^T + b_bridge)  (consumes efb; hp = scratch)
    k_gemm<0><<<dim3(16, 1), 256, 0, stream>>>(efb, 2048, wbb, 2048, hp, 1024, 2048);
    k_h0act<<<256, 256, 0, stream>>>(hp, bb, h0f, hbf);
    // reset barrier vars + per-batch counters (stream-ordered, deterministic per call)
    (void)hipMemsetAsync(syncb, 0, 32768, stream);
    // proj_key = encoder_hidden @ W_key^T  (bf16 out): M=8192, N=1024, K=2048
    k_gemm128<1><<<dim3(8, 64), 256, 0, stream>>>(ehb, 2048, wkb, 2048, pkb, 1024, 2048);
    // gi_x = trg_embed @ W_ih[:, :E]^T  (f32 out): M=8192, N=3072, K=1024
    k_gemm128<0><<<dim3(24, 64), 256, 0, stream>>>(preC, 4096, wihb, 3072, gix, 3072, 1024);

    // persistent step loop: 256 blocks x 1024 threads, eh pinned in LDS, 2 gbars/step
    k_steps<<<NBLK, 1024, 0, stream>>>(pkb, ehb, whpb, wihb, We, gix, bih, bhh,
                                       h0f, hbf, preC, o_states, o_hf, syncb, scb);

    // pre_output = [x_t, h_t, ctx_t] @ W_pre^T: M=8192, N=2048, K=4096
    k_gemm128<0><<<dim3(16, 64), 256, 0, stream>>>(preC, 4096, wpreb, 4096, o_pre, 2048, 4096);
}

// Round 19
// 5343.067 us; speedup vs baseline: 1.2353x; 1.2353x over previous
//
#include <hip/hip_runtime.h>
#include <hip/hip_bf16.h>

// ---------- types ----------
typedef short    bf16x8 __attribute__((ext_vector_type(8)));   // 8 bf16 (4 VGPRs), MFMA A/B frag
typedef float    f32x4  __attribute__((ext_vector_type(4)));   // MFMA C/D frag
typedef unsigned short u16x8 __attribute__((ext_vector_type(8)));

#define B_  64
#define S_  128
#define T_  128
#define E_  1024
#define H_  1024
#define NBLK 256

#define RLX __ATOMIC_RELAXED
#define AGT __HIP_MEMORY_SCOPE_AGENT

__device__ __forceinline__ unsigned short f2bf(float f) {
    unsigned u = __float_as_uint(f);
    unsigned r = (u + 0x7FFFu + ((u >> 16) & 1u)) >> 16;   // RNE
    return (unsigned short)r;
}
__device__ __forceinline__ float bf2f(unsigned short u) {
    return __uint_as_float((unsigned)u << 16);
}
__device__ __forceinline__ float my_tanh(float x) {
    float e = __expf(2.0f * x);
    return 1.0f - 2.0f / (e + 1.0f);
}
__device__ __forceinline__ float my_sig(float x) {
    return 1.0f / (1.0f + __expf(-x));
}

// ---------- coherent (L2-bypass) relaxed accessors ----------
__device__ __forceinline__ void st8c(void* p, unsigned long long v) {
    __hip_atomic_store((unsigned long long*)p, v, RLX, AGT);
}
__device__ __forceinline__ unsigned long long ld8c(const void* p) {
    return __hip_atomic_load((const unsigned long long*)p, RLX, AGT);
}
__device__ __forceinline__ void st4c(void* p, unsigned v) {
    __hip_atomic_store((unsigned*)p, v, RLX, AGT);
}
__device__ __forceinline__ void st4f(void* p, float v) {
    __hip_atomic_store((float*)p, v, RLX, AGT);
}
__device__ __forceinline__ float ld4f(const void* p) {
    return __hip_atomic_load((const float*)p, RLX, AGT);
}
__device__ __forceinline__ void cadd(int* p) {
    __hip_atomic_fetch_add(p, 1, RLX, AGT);
}
__device__ __forceinline__ void cwait(int* p, int target) {
    while (__hip_atomic_load(p, RLX, AGT) < target)
        __builtin_amdgcn_s_sleep(2);
}

// ---------- async global->LDS (16B per lane; LDS dest = wave base + lane*16) ----------
__device__ __forceinline__ void gld_lds16(const void* g, void* l) {
    __builtin_amdgcn_global_load_lds(
        (const __attribute__((address_space(1))) unsigned int*)(unsigned long long)g,
        (__attribute__((address_space(3))) unsigned int*)(unsigned int)(unsigned long long)l,
        16, 0, 0);
}

// ---------- f32 -> bf16 conversion ----------
__global__ void k_cvt(const float* __restrict__ s, unsigned short* __restrict__ d, long n) {
    long i = ((long)blockIdx.x * blockDim.x + threadIdx.x) * 4;
    if (i >= n) return;
    float4 f = *(const float4*)(s + i);
    ushort4 o;
    o.x = f2bf(f.x); o.y = f2bf(f.y); o.z = f2bf(f.z); o.w = f2bf(f.w);
    *(ushort4*)(d + i) = o;
}

// trg_embed (B,T,1024) -> preC[(b*T+t)*4096 + 0..1023]
__global__ void k_cvt_te(const float* __restrict__ s, unsigned short* __restrict__ d, long n) {
    long i = ((long)blockIdx.x * blockDim.x + threadIdx.x) * 4;
    if (i >= n) return;
    float4 f = *(const float4*)(s + i);
    long row = i >> 10, col = i & 1023;
    ushort4 o;
    o.x = f2bf(f.x); o.y = f2bf(f.y); o.z = f2bf(f.z); o.w = f2bf(f.w);
    *(ushort4*)(d + row * 4096 + col) = o;
}

// ---------- small MFMA GEMM (h0 only): C[M,N] = A[M,K] @ W[N,K]^T ----------
template<int OUTBF>
__global__ __launch_bounds__(256) void k_gemm(const unsigned short* __restrict__ A, long lda,
                                              const unsigned short* __restrict__ W, long ldw,
                                              void* __restrict__ Cv, long ldc, int K) {
    const int lane = threadIdx.x & 63;
    const int wv   = threadIdx.x >> 6;
    const int r    = lane & 15, g = lane >> 4;
    const long m0  = (long)blockIdx.y * 64 + wv * 16;
    const long n0  = (long)blockIdx.x * 64;
    const unsigned short* a  = A + (m0 + r) * lda + g * 8;
    const unsigned short* w0 = W + (n0 + r) * ldw + g * 8;
    f32x4 acc[4] = {};
    for (int k = 0; k < K; k += 32) {
        bf16x8 av = *(const bf16x8*)(a + k);
#pragma unroll
        for (int j = 0; j < 4; ++j) {
            bf16x8 bv = *(const bf16x8*)(w0 + (long)j * 16 * ldw + k);
            acc[j] = __builtin_amdgcn_mfma_f32_16x16x32_bf16(av, bv, acc[j], 0, 0, 0);
        }
    }
#pragma unroll
    for (int j = 0; j < 4; ++j) {
        long row = m0 + g * 4;
        long col = n0 + j * 16 + r;
#pragma unroll
        for (int rr = 0; rr < 4; ++rr) {
            float v = acc[j][rr];
            if (OUTBF) ((unsigned short*)Cv)[(row + rr) * ldc + col] = f2bf(v);
            else       ((float*)Cv)[(row + rr) * ldc + col] = v;
        }
    }
}

// ---------- m97-style 128x128 GEMM: global_load_lds staging, 4 waves (2x2), BK=32 ----------
template<int OUTBF>
__global__ __launch_bounds__(256) void k_gemm128(const unsigned short* __restrict__ A, long lda,
                                                 const unsigned short* __restrict__ W, long ldw,
                                                 void* __restrict__ Cv, long ldc, int K) {
    __shared__ unsigned short lA[128 * 32];
    __shared__ unsigned short lB[128 * 32];
    const int tid  = threadIdx.x;
    const int lane = tid & 63, wv = tid >> 6;
    const int r = lane & 15, gg = lane >> 4;
    const int wm = (wv >> 1) * 64, wn = (wv & 1) * 64;
    const long m0 = (long)blockIdx.y * 128;
    const long n0 = (long)blockIdx.x * 128;
    const int c0 = 2 * wv, c1 = 2 * wv + 1;
    const int ra0 = c0 * 16 + (lane >> 2);
    const int ra1 = c1 * 16 + (lane >> 2);
    const int cb8 = (lane & 3) * 8;
    const unsigned short* a0 = A + (m0 + ra0) * lda + cb8;
    const unsigned short* a1 = A + (m0 + ra1) * lda + cb8;
    const unsigned short* b0 = W + (n0 + ra0) * ldw + cb8;
    const unsigned short* b1 = W + (n0 + ra1) * ldw + cb8;
    f32x4 acc[4][4] = {};
    for (int k0 = 0; k0 < K; k0 += 32) {
        __syncthreads();
        gld_lds16(a0 + k0, &lA[c0 * 512]);
        gld_lds16(a1 + k0, &lA[c1 * 512]);
        gld_lds16(b0 + k0, &lB[c0 * 512]);
        gld_lds16(b1 + k0, &lB[c1 * 512]);
        __syncthreads();
        bf16x8 av[4], bv[4];
#pragma unroll
        for (int i = 0; i < 4; ++i) {
            av[i] = *(const bf16x8*)&lA[(wm + i * 16 + r) * 32 + gg * 8];
            bv[i] = *(const bf16x8*)&lB[(wn + i * 16 + r) * 32 + gg * 8];
        }
#pragma unroll
        for (int mi = 0; mi < 4; ++mi)
#pragma unroll
            for (int ni = 0; ni < 4; ++ni)
                acc[mi][ni] = __builtin_amdgcn_mfma_f32_16x16x32_bf16(av[mi], bv[ni], acc[mi][ni], 0, 0, 0);
    }
#pragma unroll
    for (int mi = 0; mi < 4; ++mi) {
#pragma unroll
        for (int ni = 0; ni < 4; ++ni) {
            const long col = n0 + wn + ni * 16 + r;
#pragma unroll
            for (int rr = 0; rr < 4; ++rr) {
                const long row = m0 + wm + mi * 16 + gg * 4 + rr;
                float v = acc[mi][ni][rr];
                if (OUTBF) ((unsigned short*)Cv)[row * ldc + col] = f2bf(v);
                else       ((float*)Cv)[row * ldc + col] = v;
            }
        }
    }
}

// ---------- h0 activation ----------
__global__ void k_h0act(const float* __restrict__ hp, const float* __restrict__ bb,
                        float* __restrict__ h, unsigned short* __restrict__ hbf) {
    int i = blockIdx.x * 256 + threadIdx.x;   // 65536
    float v = my_tanh(hp[i] + bb[i & 1023]);
    h[i] = v; hbf[i] = f2bf(v);
}

// ---------- persistent step loop: 256 blocks x 1024 thr ----------
// Round-16 compute (XCD-stable mappings, eh pinned in LDS, dedup'd energy) with ALL grid
// barriers replaced by point-to-point monotonic producer counters:
//   qcnt[bq]   += by P1 blocks cb<16   ; P2 waits 16*(t+1)   (q ready)
//   ghcnt[bq]  += by P1 blocks cb>=16  ; P3 waits 48*(t+1)   (gh ready)
//   ctxcnt[bg] += by P2 blocks         ; P3 waits 64*(t+1)   (ctx ready)
//   hcnt[bq]   += by P3 blocks         ; P1 waits 64*t       (h_{t-1} ready)
__global__ __launch_bounds__(1024) void k_steps(
        const unsigned short* __restrict__ pk, const unsigned short* __restrict__ eh,
        const unsigned short* __restrict__ whp, const unsigned short* __restrict__ wih,
        const float* __restrict__ We, const float* __restrict__ gix,
        const float* __restrict__ bih, const float* __restrict__ bhh,
        const float* __restrict__ h0f, const unsigned short* __restrict__ hbf,
        float* __restrict__ hp, unsigned short* __restrict__ preC,
        float* __restrict__ o_states, float* __restrict__ o_hf,
        int* __restrict__ sync, float* __restrict__ scb) {
    __shared__ unsigned short ehs[S_ * 512];  // 128 KB: eh[p2_b][:, q4*512 .. +512) resident
    __shared__ float smf[16 * 64 * 4];        // 16 KB, reused per phase
    __shared__ unsigned short hsm[256];
    const int g    = blockIdx.x;
    const int tid  = threadIdx.x;
    const int wv   = tid >> 6, lane = tid & 63;
    const int r    = lane & 15, gg = lane >> 4;

    // ---- P1 roles: XCD (g&7) pins the whp col-slice; bq from high bits ----
    const int p1_bq = g >> 6;                             // batch-quarter 0..3
    const int p1_cb = (g & 7) * 8 + ((g >> 3) & 7);       // 64-col tile 0..63 (8 per XCD)
    const int p1_ct = wv & 3, p1_ks = wv >> 2;
    // ---- P2 roles: block = (batch, col-quarter); 4 blocks/batch on same XCD ----
    const int p2_b  = (g & 7) * 8 + (g >> 5);
    const int p2_q4 = (g >> 3) & 3;
    // ---- P3 roles: XCD (g&7) pins the wih j-slice; batch-group from high bits ----
    const int bg = g >> 6;                                // batch-group 0..3
    const int jt = (g & 7) * 8 + ((g >> 3) & 7);          // j-tile 0..63 (8 per XCD)
    const int j0 = jt * 16, b0 = bg * 16;
    const int lr = tid >> 4, lc = tid & 15;
    float hreg = (tid < 256) ? h0f[(long)(b0 + lr) * 1024 + j0 + lc] : 0.f;

    // point-to-point counters (each on its own cacheline)
    int* qcnt  = sync + 8192  + p1_bq * 32;
    int* ghcnt = sync + 8320  + p1_bq * 32;
    int* qwait = sync + 8192  + (p2_b >> 4) * 32;
    int* ctxw  = sync + 8448  + (p2_b >> 4) * 32;         // P2 adds to its batch-group
    int* ghw   = sync + 8320  + bg * 32;                  // P3 waits
    int* ctxr  = sync + 8448  + bg * 32;                  // P3 waits
    int* hadd  = sync + 8576  + bg * 32;                  // P3 adds
    int* hwait = sync + 8576  + p1_bq * 32;               // P1 waits

    // ---- one-time: stage this block's eh slice into LDS (128 rows x 512 cols bf16) ----
    {
        const unsigned short* src = eh + (long)p2_b * S_ * 2048 + p2_q4 * 512;
#pragma unroll
        for (int it = 0; it < 8; ++it) {
            int i = it * 1024 + tid;              // 8192 chunks of 8 ushorts
            int row = i >> 6, c8i = (i & 63) * 8;
            *(u16x8*)&ehs[row * 512 + c8i] = *(const u16x8*)(src + (long)row * 2048 + c8i);
        }
    }
    __syncthreads();

#pragma unroll 1
    for (int t = 0; t < T_; ++t) {
        // ======== P1: hp[64,4096] = h_{t-1} @ whp^T ; 16 rows x 64 cols per block ========
        {
            if (tid == 0) cwait(hwait, 64 * t);           // h_{t-1} of my batch-quarter ready
            __syncthreads();
            const int n0 = p1_cb * 64 + p1_ct * 16;
            const int k0 = p1_ks * 256;
            const int b  = p1_bq * 16 + r;
            const unsigned short* arow = (t == 0)
                ? hbf + (long)b * 1024 + k0 + gg * 8
                : preC + ((long)b * T_ + (t - 1)) * 4096 + 1024 + k0 + gg * 8;   // plain
            const unsigned short* bw = whp + (long)(n0 + r) * 1024 + k0 + gg * 8;
            f32x4 acc = {};
#pragma unroll
            for (int k = 0; k < 256; k += 32) {
                bf16x8 av = *(const bf16x8*)(arow + k);
                bf16x8 bv = *(const bf16x8*)(bw + k);
                acc = __builtin_amdgcn_mfma_f32_16x16x32_bf16(av, bv, acc, 0, 0, 0);
            }
            *(f32x4*)&smf[(wv * 64 + lane) * 4] = acc;
            __syncthreads();
            if (p1_ks == 0) {   // wv == p1_ct
                f32x4 s0 = *(f32x4*)&smf[((0 * 4 + p1_ct) * 64 + lane) * 4];
                f32x4 s1 = *(f32x4*)&smf[((1 * 4 + p1_ct) * 64 + lane) * 4];
                f32x4 s2 = *(f32x4*)&smf[((2 * 4 + p1_ct) * 64 + lane) * 4];
                f32x4 s3 = *(f32x4*)&smf[((3 * 4 + p1_ct) * 64 + lane) * 4];
                f32x4 s = s0 + s1 + s2 + s3;
#pragma unroll
                for (int rr = 0; rr < 4; ++rr)
                    st4f(&hp[(long)(p1_bq * 16 + gg * 4 + rr) * 4096 + n0 + r], s[rr]);
            }
            __syncthreads();                              // drain vmcnt: hp stores visible
            if (tid == 0) cadd(p1_cb < 16 ? qcnt : ghcnt);
        }

        // ======== P2: attention; energy dedup'd (32 scores/block) + sc1 exchange ========
        {
            const int b = p2_b;
            if (tid == 0) cwait(qwait, 16 * (t + 1));     // q of my batch ready
            __syncthreads();
            // --- energy: wave wv computes scores s = q4*32 + wv*2 + {0,1}; lane: 16 h ---
            const int hh = lane * 16;
            float q[16], w16[16];
#pragma unroll
            for (int i = 0; i < 8; ++i) {
                unsigned long long u = ld8c(hp + (long)b * 4096 + hh + 2 * i);
                q[2 * i]     = __uint_as_float((unsigned)u);
                q[2 * i + 1] = __uint_as_float((unsigned)(u >> 32));
            }
#pragma unroll
            for (int i = 0; i < 16; ++i) w16[i] = We[hh + i];
#pragma unroll
            for (int k2 = 0; k2 < 2; ++k2) {
                const int s = p2_q4 * 32 + wv * 2 + k2;
                const unsigned short* row = pk + ((long)b * S_ + s) * 1024 + hh;
                u16x8 v0 = *(const u16x8*)(row);
                u16x8 v1 = *(const u16x8*)(row + 8);
                float acc = 0.f;
#pragma unroll
                for (int i = 0; i < 8; ++i) acc += my_tanh(q[i] + bf2f(v0[i])) * w16[i];
#pragma unroll
                for (int i = 0; i < 8; ++i) acc += my_tanh(q[8 + i] + bf2f(v1[i])) * w16[8 + i];
#pragma unroll
                for (int off = 32; off; off >>= 1) acc += __shfl_xor(acc, off);
                if (lane == 0) st4f(&scb[b * 128 + s], acc);
            }
            // --- 4-block mini-barrier (per-batch monotonic counter) ---
            __syncthreads();                 // drains vmcnt: score stores at coherence point
            if (tid == 0) {
                int* bc = sync + 4096 + b * 32;
                cadd(bc);
                cwait(bc, 4 * (t + 1));
            }
            __syncthreads();
            // --- softmax over 128 (threads 0..127), scores from scb (sc1) ---
            float* red = &smf[648];
            float e = 0.f, sc = 0.f;
            if (tid < 128) {
                sc = ld4f(&scb[b * 128 + tid]);
                float m = sc;
#pragma unroll
                for (int off = 32; off; off >>= 1) m = fmaxf(m, __shfl_xor(m, off));
                if ((tid & 63) == 0) red[tid >> 6] = m;
            }
            __syncthreads();
            if (tid < 128) {
                float M = fmaxf(red[0], red[1]);
                e = __expf(sc - M);
                float s = e;
#pragma unroll
                for (int off = 32; off; off >>= 1) s += __shfl_xor(s, off);
                if ((tid & 63) == 0) red[2 + (tid >> 6)] = s;
            }
            __syncthreads();
            if (tid < 128) smf[512 + tid] = e / (red[2] + red[3]);
            __syncthreads();
            // --- context: thread = (col-pair cp, s-segment sseg of 32); LDS source ---
            const int cp = tid & 255, sseg = tid >> 8;
            const unsigned short* ehp = ehs + (sseg * 32) * 512 + cp * 2;
            float a0 = 0.f, a1 = 0.f;
#pragma unroll 4
            for (int s2 = 0; s2 < 32; ++s2) {
                float alv = smf[512 + sseg * 32 + s2];
                ushort2 v = *(const ushort2*)(ehp + s2 * 512);
                a0 += alv * bf2f(v.x); a1 += alv * bf2f(v.y);
            }
            smf[1024 + (sseg * 256 + cp) * 2]     = a0;
            smf[1024 + (sseg * 256 + cp) * 2 + 1] = a1;
            __syncthreads();
            if (tid < 256) {
                float b0s = smf[1024 + tid * 2]         + smf[1024 + (256 + tid) * 2]
                          + smf[1024 + (512 + tid) * 2] + smf[1024 + (768 + tid) * 2];
                float b1s = smf[1024 + tid * 2 + 1]         + smf[1024 + (256 + tid) * 2 + 1]
                          + smf[1024 + (512 + tid) * 2 + 1] + smf[1024 + (768 + tid) * 2 + 1];
                unsigned pack = (unsigned)f2bf(b0s) | ((unsigned)f2bf(b1s) << 16);
                st4c(preC + ((long)b * T_ + t) * 4096 + 2048 + p2_q4 * 512 + tid * 2, pack);
            }
            __syncthreads();                              // drain vmcnt: ctx stores visible
            if (tid == 0) cadd(ctxw);
        }

        // ======== P3: gi_ctx MFMA + GRU gates; wave = (gate, k-slice of 512) ========
        {
            if (tid == 0) { cwait(ghw, 48 * (t + 1)); cwait(ctxr, 64 * (t + 1)); }
            __syncthreads();
            if (wv < 12) {
                const int c = wv >> 2, ks = wv & 3, k0 = ks * 512;
                const unsigned short* ar = preC + ((long)(b0 + r) * T_ + t) * 4096 + 2048 + k0 + gg * 8; // plain
                const unsigned short* bw = wih + ((long)(c * 1024 + j0 + r)) * 3072 + 1024 + k0 + gg * 8;
                f32x4 acc = {};
#pragma unroll
                for (int k = 0; k < 512; k += 32) {
                    bf16x8 av = *(const bf16x8*)(ar + k);
                    bf16x8 bv = *(const bf16x8*)(bw + k);
                    acc = __builtin_amdgcn_mfma_f32_16x16x32_bf16(av, bv, acc, 0, 0, 0);
                }
                *(f32x4*)&smf[(wv * 64 + lane) * 4] = acc;
            }
            __syncthreads();
            if (tid < 256) {
                const int lane_ = (lr >> 2) * 16 + lc, rr_ = lr & 3;
                float gi[3];
#pragma unroll
                for (int c = 0; c < 3; ++c) {
                    gi[c] = smf[((c * 4 + 0) * 64 + lane_) * 4 + rr_]
                          + smf[((c * 4 + 1) * 64 + lane_) * 4 + rr_]
                          + smf[((c * 4 + 2) * 64 + lane_) * 4 + rr_]
                          + smf[((c * 4 + 3) * 64 + lane_) * 4 + rr_];
                }
                const int b = b0 + lr, j = j0 + lc;
                const long bt = (long)b * T_ + t;
                float ghr = ld4f(&hp[(long)b * 4096 + 1024 + j]);
                float ghz = ld4f(&hp[(long)b * 4096 + 2048 + j]);
                float ghn = ld4f(&hp[(long)b * 4096 + 3072 + j]);
                float grv = gix[bt * 3072 + j]        + gi[0] + bih[j]        + ghr + bhh[j];
                float gzv = gix[bt * 3072 + 1024 + j] + gi[1] + bih[1024 + j] + ghz + bhh[1024 + j];
                float gni = gix[bt * 3072 + 2048 + j] + gi[2] + bih[2048 + j];
                float ghn2 = ghn + bhh[2048 + j];
                float rg = my_sig(grv);
                float zg = my_sig(gzv);
                float nv = my_tanh(gni + rg * ghn2);
                float hn = (1.f - zg) * nv + zg * hreg;
                hreg = hn;
                unsigned short hb16 = f2bf(hn);
                o_states[bt * 1024 + j] = hn;                    // plain (read after kernel)
                if (t == T_ - 1) o_hf[(long)b * 1024 + j] = hn;  // plain
                hsm[tid] = hb16;
            }
            __syncthreads();
            // pack h_t -> preC h-slot (sc1; next-step P1 reads plain)
            if (tid < 64) {
                const int plr = tid >> 2, pc4 = (tid & 3) * 4;
                unsigned long long v =
                      (unsigned long long)hsm[plr * 16 + pc4]
                    | ((unsigned long long)hsm[plr * 16 + pc4 + 1] << 16)
                    | ((unsigned long long)hsm[plr * 16 + pc4 + 2] << 32)
                    | ((unsigned long long)hsm[plr * 16 + pc4 + 3] << 48);
                st8c(preC + ((long)(b0 + plr) * T_ + t) * 4096 + 1024 + j0 + pc4, v);
            }
            __syncthreads();                              // drain vmcnt: h stores visible
            if (tid == 0) cadd(hadd);
        }
    }
}

// ---------- host ----------
extern "C" void kernel_launch(void* const* d_in, const int* in_sizes, int n_in,
                              void* d_out, int out_size, void* d_ws, size_t ws_size,
                              hipStream_t stream) {
    const float* te  = (const float*)d_in[0];
    const float* eh  = (const float*)d_in[1];
    const float* ef  = (const float*)d_in[2];
    const float* Wb  = (const float*)d_in[5];
    const float* bb  = (const float*)d_in[6];
    const float* Wk  = (const float*)d_in[7];
    const float* Wq  = (const float*)d_in[8];
    const float* We  = (const float*)d_in[9];
    const float* Wih = (const float*)d_in[10];
    const float* Whh = (const float*)d_in[11];
    const float* bih = (const float*)d_in[12];
    const float* bhh = (const float*)d_in[13];
    const float* Wpre= (const float*)d_in[14];

    char* ws = (char*)d_ws;
    if (ws_size < 272236544UL) return;   // loud failure (output stays poisoned)
    float*          h0f   = (float*)(ws + 0);                  // 64*1024*4
    float*          hp    = (float*)(ws + 262144);             // 64*4096*4
    unsigned short* hbf   = (unsigned short*)(ws + 1310720);   // 64*1024*2 (h0 only)
    unsigned short* efb   = (unsigned short*)(ws + 1441792);   // 64*2048*2 (init only)
    int*            syncb = (int*)(ws + 1441792 + 65536);      // counters (64 KB region)
    float*          scb   = (float*)(ws + 1572864);            // 64*128*4 score exchange
    unsigned short* ehb   = (unsigned short*)(ws + 1703936);   // B*S*2048*2
    unsigned short* pkb   = (unsigned short*)(ws + 35258368);  // B*S*1024*2
    unsigned short* preC  = (unsigned short*)(ws + 52035584);  // B*T*4096*2
    float*          gix   = (float*)(ws + 119144448);          // B*T*3072*4
    unsigned short* wbb   = (unsigned short*)(ws + 219807744); // 1024*2048*2
    unsigned short* wkb   = (unsigned short*)(ws + 224002048); // 1024*2048*2
    unsigned short* whpb  = (unsigned short*)(ws + 228196352); // 4096*1024*2  [Wq; Whh]
    unsigned short* wihb  = (unsigned short*)(ws + 236584960); // 3072*3072*2
    unsigned short* wpreb = (unsigned short*)(ws + 255459328); // 2048*4096*2

    float* o_states = (float*)d_out;                 // (B,T,H)
    float* o_hf     = o_states + (long)B_ * T_ * H_; // (1,B,H)
    float* o_pre    = o_hf + (long)B_ * H_;          // (B,T,2H)

    auto cvt = [&](const float* s, unsigned short* d, long n) {
        k_cvt<<<dim3((unsigned)((n / 4 + 255) / 256)), 256, 0, stream>>>(s, d, n);
    };
    cvt(eh,  ehb,  (long)B_ * S_ * 2048);
    cvt(ef,  efb,  (long)B_ * 2048);
    cvt(Wb,  wbb,  1024L * 2048);
    cvt(Wk,  wkb,  1024L * 2048);
    cvt(Wq,  whpb, 1024L * 1024);
    cvt(Whh, whpb + 1024L * 1024, 3072L * 1024);
    cvt(Wih, wihb, 3072L * 3072);
    cvt(Wpre,wpreb,2048L * 4096);
    k_cvt_te<<<8192, 256, 0, stream>>>(te, preC, (long)B_ * T_ * 1024);

    // h0 = tanh(encoder_final @ W_bridge^T + b_bridge)  (consumes efb; hp = scratch)
    k_gemm<0><<<dim3(16, 1), 256, 0, stream>>>(efb, 2048, wbb, 2048, hp, 1024, 2048);
    k_h0act<<<256, 256, 0, stream>>>(hp, bb, h0f, hbf);
    // reset ALL counters (stream-ordered, deterministic per call)
    (void)hipMemsetAsync(syncb, 0, 65536, stream);
    // proj_key = encoder_hidden @ W_key^T  (bf16 out): M=8192, N=1024, K=2048
    k_gemm128<1><<<dim3(8, 64), 256, 0, stream>>>(ehb, 2048, wkb, 2048, pkb, 1024, 2048);
    // gi_x = trg_embed @ W_ih[:, :E]^T  (f32 out): M=8192, N=3072, K=1024
    k_gemm128<0><<<dim3(24, 64), 256, 0, stream>>>(preC, 4096, wihb, 3072, gix, 3072, 1024);

    // persistent step loop: 256 blocks x 1024 threads, eh pinned in LDS, p2p counters
    k_steps<<<NBLK, 1024, 0, stream>>>(pkb, ehb, whpb, wihb, We, gix, bih, bhh,
                                       h0f, hbf, hp, preC, o_states, o_hf, syncb, scb);

    // pre_output = [x_t, h_t, ctx_t] @ W_pre^T: M=8192, N=2048, K=4096
    k_gemm128<0><<<dim3(16, 64), 256, 0, stream>>>(preC, 4096, wpreb, 4096, o_pre, 2048, 4096);
}

// Round 20
// 5101.945 us; speedup vs baseline: 1.2937x; 1.0473x over previous
//
#include <hip/hip_runtime.h>
#include <hip/hip_bf16.h>

// ---------- types ----------
typedef short    bf16x8 __attribute__((ext_vector_type(8)));   // 8 bf16 (4 VGPRs), MFMA A/B frag
typedef float    f32x4  __attribute__((ext_vector_type(4)));   // MFMA C/D frag
typedef unsigned short u16x8 __attribute__((ext_vector_type(8)));

#define B_  64
#define S_  128
#define T_  128
#define E_  1024
#define H_  1024
#define NBLK 256

#define RLX __ATOMIC_RELAXED
#define AGT __HIP_MEMORY_SCOPE_AGENT

__device__ __forceinline__ unsigned short f2bf(float f) {
    unsigned u = __float_as_uint(f);
    unsigned r = (u + 0x7FFFu + ((u >> 16) & 1u)) >> 16;   // RNE
    return (unsigned short)r;
}
__device__ __forceinline__ float bf2f(unsigned short u) {
    return __uint_as_float((unsigned)u << 16);
}
__device__ __forceinline__ float my_tanh(float x) {
    float e = __expf(2.0f * x);
    return 1.0f - 2.0f / (e + 1.0f);
}
__device__ __forceinline__ float my_sig(float x) {
    return 1.0f / (1.0f + __expf(-x));
}

// ---------- coherent (L2-bypass) relaxed accessors ----------
__device__ __forceinline__ void st8c(void* p, unsigned long long v) {
    __hip_atomic_store((unsigned long long*)p, v, RLX, AGT);
}
__device__ __forceinline__ unsigned long long ld8c(const void* p) {
    return __hip_atomic_load((const unsigned long long*)p, RLX, AGT);
}
__device__ __forceinline__ void st4c(void* p, unsigned v) {
    __hip_atomic_store((unsigned*)p, v, RLX, AGT);
}
__device__ __forceinline__ void st4f(void* p, float v) {
    __hip_atomic_store((float*)p, v, RLX, AGT);
}
__device__ __forceinline__ float ld4f(const void* p) {
    return __hip_atomic_load((const float*)p, RLX, AGT);
}

// ---------- per-batch-quarter barrier: 64 blocks = 8 leaves x 8, relaxed atomics ----------
// s points at this bq's region: [0]=root cnt, [32]=root gen, [64+leaf*64]=leaf cnt, [+32]=leaf gen
__device__ __forceinline__ void gbarq(int* s, int leaf, int ord) {
    __syncthreads();                         // drains vmcnt -> sc1 stores at coherence point
    if (threadIdx.x == 0) {
        int* lc = s + 64 + leaf * 64;
        int* lg = lc + 32;
        if (__hip_atomic_fetch_add(lc, 1, RLX, AGT) == 8 * ord - 1) {
            if (__hip_atomic_fetch_add(s, 1, RLX, AGT) == 8 * ord - 1) {
                __hip_atomic_store(s + 32, ord, RLX, AGT);
            } else {
                while (__hip_atomic_load(s + 32, RLX, AGT) < ord)
                    __builtin_amdgcn_s_sleep(2);
            }
            __hip_atomic_store(lg, ord, RLX, AGT);
        } else {
            while (__hip_atomic_load(lg, RLX, AGT) < ord)
                __builtin_amdgcn_s_sleep(2);
        }
    }
    __syncthreads();
}

// ---------- async global->LDS (16B per lane; LDS dest = wave base + lane*16) ----------
__device__ __forceinline__ void gld_lds16(const void* g, void* l) {
    __builtin_amdgcn_global_load_lds(
        (const __attribute__((address_space(1))) unsigned int*)(unsigned long long)g,
        (__attribute__((address_space(3))) unsigned int*)(unsigned int)(unsigned long long)l,
        16, 0, 0);
}

// ---------- f32 -> bf16 conversion ----------
__global__ void k_cvt(const float* __restrict__ s, unsigned short* __restrict__ d, long n) {
    long i = ((long)blockIdx.x * blockDim.x + threadIdx.x) * 4;
    if (i >= n) return;
    float4 f = *(const float4*)(s + i);
    ushort4 o;
    o.x = f2bf(f.x); o.y = f2bf(f.y); o.z = f2bf(f.z); o.w = f2bf(f.w);
    *(ushort4*)(d + i) = o;
}

// trg_embed (B,T,1024) -> preC[(b*T+t)*4096 + 0..1023]
__global__ void k_cvt_te(const float* __restrict__ s, unsigned short* __restrict__ d, long n) {
    long i = ((long)blockIdx.x * blockDim.x + threadIdx.x) * 4;
    if (i >= n) return;
    float4 f = *(const float4*)(s + i);
    long row = i >> 10, col = i & 1023;
    ushort4 o;
    o.x = f2bf(f.x); o.y = f2bf(f.y); o.z = f2bf(f.z); o.w = f2bf(f.w);
    *(ushort4*)(d + row * 4096 + col) = o;
}

// ---------- small MFMA GEMM (h0 only): C[M,N] = A[M,K] @ W[N,K]^T ----------
template<int OUTBF>
__global__ __launch_bounds__(256) void k_gemm(const unsigned short* __restrict__ A, long lda,
                                              const unsigned short* __restrict__ W, long ldw,
                                              void* __restrict__ Cv, long ldc, int K) {
    const int lane = threadIdx.x & 63;
    const int wv   = threadIdx.x >> 6;
    const int r    = lane & 15, g = lane >> 4;
    const long m0  = (long)blockIdx.y * 64 + wv * 16;
    const long n0  = (long)blockIdx.x * 64;
    const unsigned short* a  = A + (m0 + r) * lda + g * 8;
    const unsigned short* w0 = W + (n0 + r) * ldw + g * 8;
    f32x4 acc[4] = {};
    for (int k = 0; k < K; k += 32) {
        bf16x8 av = *(const bf16x8*)(a + k);
#pragma unroll
        for (int j = 0; j < 4; ++j) {
            bf16x8 bv = *(const bf16x8*)(w0 + (long)j * 16 * ldw + k);
            acc[j] = __builtin_amdgcn_mfma_f32_16x16x32_bf16(av, bv, acc[j], 0, 0, 0);
        }
    }
#pragma unroll
    for (int j = 0; j < 4; ++j) {
        long row = m0 + g * 4;
        long col = n0 + j * 16 + r;
#pragma unroll
        for (int rr = 0; rr < 4; ++rr) {
            float v = acc[j][rr];
            if (OUTBF) ((unsigned short*)Cv)[(row + rr) * ldc + col] = f2bf(v);
            else       ((float*)Cv)[(row + rr) * ldc + col] = v;
        }
    }
}

// ---------- m97-style 128x128 GEMM: global_load_lds staging, 4 waves (2x2), BK=32 ----------
template<int OUTBF>
__global__ __launch_bounds__(256) void k_gemm128(const unsigned short* __restrict__ A, long lda,
                                                 const unsigned short* __restrict__ W, long ldw,
                                                 void* __restrict__ Cv, long ldc, int K) {
    __shared__ unsigned short lA[128 * 32];
    __shared__ unsigned short lB[128 * 32];
    const int tid  = threadIdx.x;
    const int lane = tid & 63, wv = tid >> 6;
    const int r = lane & 15, gg = lane >> 4;
    const int wm = (wv >> 1) * 64, wn = (wv & 1) * 64;
    const long m0 = (long)blockIdx.y * 128;
    const long n0 = (long)blockIdx.x * 128;
    const int c0 = 2 * wv, c1 = 2 * wv + 1;
    const int ra0 = c0 * 16 + (lane >> 2);
    const int ra1 = c1 * 16 + (lane >> 2);
    const int cb8 = (lane & 3) * 8;
    const unsigned short* a0 = A + (m0 + ra0) * lda + cb8;
    const unsigned short* a1 = A + (m0 + ra1) * lda + cb8;
    const unsigned short* b0 = W + (n0 + ra0) * ldw + cb8;
    const unsigned short* b1 = W + (n0 + ra1) * ldw + cb8;
    f32x4 acc[4][4] = {};
    for (int k0 = 0; k0 < K; k0 += 32) {
        __syncthreads();
        gld_lds16(a0 + k0, &lA[c0 * 512]);
        gld_lds16(a1 + k0, &lA[c1 * 512]);
        gld_lds16(b0 + k0, &lB[c0 * 512]);
        gld_lds16(b1 + k0, &lB[c1 * 512]);
        __syncthreads();
        bf16x8 av[4], bv[4];
#pragma unroll
        for (int i = 0; i < 4; ++i) {
            av[i] = *(const bf16x8*)&lA[(wm + i * 16 + r) * 32 + gg * 8];
            bv[i] = *(const bf16x8*)&lB[(wn + i * 16 + r) * 32 + gg * 8];
        }
#pragma unroll
        for (int mi = 0; mi < 4; ++mi)
#pragma unroll
            for (int ni = 0; ni < 4; ++ni)
                acc[mi][ni] = __builtin_amdgcn_mfma_f32_16x16x32_bf16(av[mi], bv[ni], acc[mi][ni], 0, 0, 0);
    }
#pragma unroll
    for (int mi = 0; mi < 4; ++mi) {
#pragma unroll
        for (int ni = 0; ni < 4; ++ni) {
            const long col = n0 + wn + ni * 16 + r;
#pragma unroll
            for (int rr = 0; rr < 4; ++rr) {
                const long row = m0 + wm + mi * 16 + gg * 4 + rr;
                float v = acc[mi][ni][rr];
                if (OUTBF) ((unsigned short*)Cv)[row * ldc + col] = f2bf(v);
                else       ((float*)Cv)[row * ldc + col] = v;
            }
        }
    }
}

// ---------- h0 activation ----------
__global__ void k_h0act(const float* __restrict__ hp, const float* __restrict__ bb,
                        float* __restrict__ h, unsigned short* __restrict__ hbf) {
    int i = blockIdx.x * 256 + threadIdx.x;   // 65536
    float v = my_tanh(hp[i] + bb[i & 1023]);
    h[i] = v; hbf[i] = f2bf(v);
}

// ---------- persistent step loop: 4 INDEPENDENT 64-block batch-quarter pipelines ----------
// All three phase roles of a block serve the SAME batch-quarter (bq = g>>6), so the four
// bq pipelines share only read-only weights and never synchronize with each other.
// Per-bq 64-block barriers (8 leaves x 8, leaf = same-XCD blocks); XCD-stable weight slices.
__global__ __launch_bounds__(1024) void k_steps(
        const unsigned short* __restrict__ pk, const unsigned short* __restrict__ eh,
        const unsigned short* __restrict__ whp, const unsigned short* __restrict__ wih,
        const float* __restrict__ We, const float* __restrict__ gix,
        const float* __restrict__ bih, const float* __restrict__ bhh,
        const float* __restrict__ h0f, const unsigned short* __restrict__ hbf,
        float* __restrict__ hp, unsigned short* __restrict__ preC,
        float* __restrict__ o_states, float* __restrict__ o_hf,
        int* __restrict__ sync, float* __restrict__ scb) {
    __shared__ unsigned short ehs[S_ * 512];  // 128 KB: eh[p2_b][:, q4*512 .. +512) resident
    __shared__ float smf[16 * 64 * 4];        // 16 KB, reused per phase
    __shared__ unsigned short hsm[256];
    const int g    = blockIdx.x;
    const int tid  = threadIdx.x;
    const int wv   = tid >> 6, lane = tid & 63;
    const int r    = lane & 15, gg = lane >> 4;

    // ---- bq-aligned roles: bq = g>>6, z = g&63, xcd = z&7, sub = z>>3 ----
    const int bq  = g >> 6, z = g & 63;
    const int xcd = z & 7, sub = z >> 3;
    int* bqs = sync + bq * 1024;                          // this bq's barrier region
    // P1: 16 rows (bq batches) x 64 cols; whp col-slice XCD-pinned
    const int p1_cb = xcd * 8 + sub;                      // 64-col tile 0..63 (8 per XCD)
    const int p1_ct = wv & 3, p1_ks = wv >> 2;
    // P2: batch + col-quarter, batch pinned to XCD
    const int p2_b  = bq * 16 + xcd * 2 + (sub & 1);
    const int p2_q4 = sub >> 1;
    // P3: j-tile XCD-pinned; batches = this bq
    const int jt = xcd * 8 + sub;
    const int j0 = jt * 16, b0 = bq * 16;
    const int lr = tid >> 4, lc = tid & 15;
    float hreg = (tid < 256) ? h0f[(long)(b0 + lr) * 1024 + j0 + lc] : 0.f;

    // ---- one-time: stage this block's eh slice into LDS (128 rows x 512 cols bf16) ----
    {
        const unsigned short* src = eh + (long)p2_b * S_ * 2048 + p2_q4 * 512;
#pragma unroll
        for (int it = 0; it < 8; ++it) {
            int i = it * 1024 + tid;              // 8192 chunks of 8 ushorts
            int row = i >> 6, c8i = (i & 63) * 8;
            *(u16x8*)&ehs[row * 512 + c8i] = *(const u16x8*)(src + (long)row * 2048 + c8i);
        }
    }
    __syncthreads();

    int ord = 0;

#pragma unroll 1
    for (int t = 0; t < T_; ++t) {
        // ======== P1: hp[bq rows, 4096] = h_{t-1} @ whp^T ; 16 rows x 64 cols per block ====
        {
            const int n0 = p1_cb * 64 + p1_ct * 16;
            const int k0 = p1_ks * 256;
            const int b  = bq * 16 + r;
            const unsigned short* arow = (t == 0)
                ? hbf + (long)b * 1024 + k0 + gg * 8
                : preC + ((long)b * T_ + (t - 1)) * 4096 + 1024 + k0 + gg * 8;   // plain
            const unsigned short* bw = whp + (long)(n0 + r) * 1024 + k0 + gg * 8;
            f32x4 acc = {};
#pragma unroll
            for (int k = 0; k < 256; k += 32) {
                bf16x8 av = *(const bf16x8*)(arow + k);
                bf16x8 bv = *(const bf16x8*)(bw + k);
                acc = __builtin_amdgcn_mfma_f32_16x16x32_bf16(av, bv, acc, 0, 0, 0);
            }
            *(f32x4*)&smf[(wv * 64 + lane) * 4] = acc;
            __syncthreads();
            if (p1_ks == 0) {   // wv == p1_ct
                f32x4 s0 = *(f32x4*)&smf[((0 * 4 + p1_ct) * 64 + lane) * 4];
                f32x4 s1 = *(f32x4*)&smf[((1 * 4 + p1_ct) * 64 + lane) * 4];
                f32x4 s2 = *(f32x4*)&smf[((2 * 4 + p1_ct) * 64 + lane) * 4];
                f32x4 s3 = *(f32x4*)&smf[((3 * 4 + p1_ct) * 64 + lane) * 4];
                f32x4 s = s0 + s1 + s2 + s3;
#pragma unroll
                for (int rr = 0; rr < 4; ++rr)
                    st4f(&hp[(long)(bq * 16 + gg * 4 + rr) * 4096 + n0 + r], s[rr]);
            }
        }
        gbarq(bqs, xcd, ++ord);

        // ======== P2: attention; energy dedup'd (32 scores/block) + sc1 exchange ========
        {
            const int b = p2_b;
            // --- energy: wave wv computes scores s = q4*32 + wv*2 + {0,1}; lane: 16 h ---
            const int hh = lane * 16;
            float q[16], w16[16];
#pragma unroll
            for (int i = 0; i < 8; ++i) {
                unsigned long long u = ld8c(hp + (long)b * 4096 + hh + 2 * i);
                q[2 * i]     = __uint_as_float((unsigned)u);
                q[2 * i + 1] = __uint_as_float((unsigned)(u >> 32));
            }
#pragma unroll
            for (int i = 0; i < 16; ++i) w16[i] = We[hh + i];
#pragma unroll
            for (int k2 = 0; k2 < 2; ++k2) {
                const int s = p2_q4 * 32 + wv * 2 + k2;
                const unsigned short* row = pk + ((long)b * S_ + s) * 1024 + hh;
                u16x8 v0 = *(const u16x8*)(row);
                u16x8 v1 = *(const u16x8*)(row + 8);
                float acc = 0.f;
#pragma unroll
                for (int i = 0; i < 8; ++i) acc += my_tanh(q[i] + bf2f(v0[i])) * w16[i];
#pragma unroll
                for (int i = 0; i < 8; ++i) acc += my_tanh(q[8 + i] + bf2f(v1[i])) * w16[8 + i];
#pragma unroll
                for (int off = 32; off; off >>= 1) acc += __shfl_xor(acc, off);
                if (lane == 0) st4f(&scb[b * 128 + s], acc);
            }
            // --- 4-block mini-barrier (per-batch monotonic counter) ---
            __syncthreads();                 // drains vmcnt: score stores at coherence point
            if (tid == 0) {
                int* bc = sync + 4096 + b * 32;
                __hip_atomic_fetch_add(bc, 1, RLX, AGT);
                while (__hip_atomic_load(bc, RLX, AGT) < 4 * (t + 1))
                    __builtin_amdgcn_s_sleep(2);
            }
            __syncthreads();
            // --- softmax over 128 (threads 0..127), scores from scb (sc1) ---
            float* red = &smf[648];
            float e = 0.f, sc = 0.f;
            if (tid < 128) {
                sc = ld4f(&scb[b * 128 + tid]);
                float m = sc;
#pragma unroll
                for (int off = 32; off; off >>= 1) m = fmaxf(m, __shfl_xor(m, off));
                if ((tid & 63) == 0) red[tid >> 6] = m;
            }
            __syncthreads();
            if (tid < 128) {
                float M = fmaxf(red[0], red[1]);
                e = __expf(sc - M);
                float s = e;
#pragma unroll
                for (int off = 32; off; off >>= 1) s += __shfl_xor(s, off);
                if ((tid & 63) == 0) red[2 + (tid >> 6)] = s;
            }
            __syncthreads();
            if (tid < 128) smf[512 + tid] = e / (red[2] + red[3]);
            __syncthreads();
            // --- context: thread = (col-pair cp, s-segment sseg of 32); LDS source ---
            const int cp = tid & 255, sseg = tid >> 8;
            const unsigned short* ehp = ehs + (sseg * 32) * 512 + cp * 2;
            float a0 = 0.f, a1 = 0.f;
#pragma unroll 4
            for (int s2 = 0; s2 < 32; ++s2) {
                float alv = smf[512 + sseg * 32 + s2];
                ushort2 v = *(const ushort2*)(ehp + s2 * 512);
                a0 += alv * bf2f(v.x); a1 += alv * bf2f(v.y);
            }
            smf[1024 + (sseg * 256 + cp) * 2]     = a0;
            smf[1024 + (sseg * 256 + cp) * 2 + 1] = a1;
            __syncthreads();
            if (tid < 256) {
                float b0s = smf[1024 + tid * 2]         + smf[1024 + (256 + tid) * 2]
                          + smf[1024 + (512 + tid) * 2] + smf[1024 + (768 + tid) * 2];
                float b1s = smf[1024 + tid * 2 + 1]         + smf[1024 + (256 + tid) * 2 + 1]
                          + smf[1024 + (512 + tid) * 2 + 1] + smf[1024 + (768 + tid) * 2 + 1];
                unsigned pack = (unsigned)f2bf(b0s) | ((unsigned)f2bf(b1s) << 16);
                st4c(preC + ((long)b * T_ + t) * 4096 + 2048 + p2_q4 * 512 + tid * 2, pack);
            }
        }
        gbarq(bqs, xcd, ++ord);

        // ======== P3: gi_ctx MFMA + GRU gates; wave = (gate, k-slice of 512) ========
        {
            if (wv < 12) {
                const int c = wv >> 2, ks = wv & 3, k0 = ks * 512;
                const unsigned short* ar = preC + ((long)(b0 + r) * T_ + t) * 4096 + 2048 + k0 + gg * 8; // plain
                const unsigned short* bw = wih + ((long)(c * 1024 + j0 + r)) * 3072 + 1024 + k0 + gg * 8;
                f32x4 acc = {};
#pragma unroll
                for (int k = 0; k < 512; k += 32) {
                    bf16x8 av = *(const bf16x8*)(ar + k);
                    bf16x8 bv = *(const bf16x8*)(bw + k);
                    acc = __builtin_amdgcn_mfma_f32_16x16x32_bf16(av, bv, acc, 0, 0, 0);
                }
                *(f32x4*)&smf[(wv * 64 + lane) * 4] = acc;
            }
            __syncthreads();
            if (tid < 256) {
                const int lane_ = (lr >> 2) * 16 + lc, rr_ = lr & 3;
                float gi[3];
#pragma unroll
                for (int c = 0; c < 3; ++c) {
                    gi[c] = smf[((c * 4 + 0) * 64 + lane_) * 4 + rr_]
                          + smf[((c * 4 + 1) * 64 + lane_) * 4 + rr_]
                          + smf[((c * 4 + 2) * 64 + lane_) * 4 + rr_]
                          + smf[((c * 4 + 3) * 64 + lane_) * 4 + rr_];
                }
                const int b = b0 + lr, j = j0 + lc;
                const long bt = (long)b * T_ + t;
                float ghr = ld4f(&hp[(long)b * 4096 + 1024 + j]);
                float ghz = ld4f(&hp[(long)b * 4096 + 2048 + j]);
                float ghn = ld4f(&hp[(long)b * 4096 + 3072 + j]);
                float grv = gix[bt * 3072 + j]        + gi[0] + bih[j]        + ghr + bhh[j];
                float gzv = gix[bt * 3072 + 1024 + j] + gi[1] + bih[1024 + j] + ghz + bhh[1024 + j];
                float gni = gix[bt * 3072 + 2048 + j] + gi[2] + bih[2048 + j];
                float ghn2 = ghn + bhh[2048 + j];
                float rg = my_sig(grv);
                float zg = my_sig(gzv);
                float nv = my_tanh(gni + rg * ghn2);
                float hn = (1.f - zg) * nv + zg * hreg;
                hreg = hn;
                unsigned short hb16 = f2bf(hn);
                o_states[bt * 1024 + j] = hn;                    // plain (read after kernel)
                if (t == T_ - 1) o_hf[(long)b * 1024 + j] = hn;  // plain
                hsm[tid] = hb16;
            }
            __syncthreads();
            // pack h_t -> preC h-slot (sc1; next-step P1 reads plain)
            if (tid < 64) {
                const int plr = tid >> 2, pc4 = (tid & 3) * 4;
                unsigned long long v =
                      (unsigned long long)hsm[plr * 16 + pc4]
                    | ((unsigned long long)hsm[plr * 16 + pc4 + 1] << 16)
                    | ((unsigned long long)hsm[plr * 16 + pc4 + 2] << 32)
                    | ((unsigned long long)hsm[plr * 16 + pc4 + 3] << 48);
                st8c(preC + ((long)(b0 + plr) * T_ + t) * 4096 + 1024 + j0 + pc4, v);
            }
        }
        gbarq(bqs, xcd, ++ord);
    }
}

// ---------- host ----------
extern "C" void kernel_launch(void* const* d_in, const int* in_sizes, int n_in,
                              void* d_out, int out_size, void* d_ws, size_t ws_size,
                              hipStream_t stream) {
    const float* te  = (const float*)d_in[0];
    const float* eh  = (const float*)d_in[1];
    const float* ef  = (const float*)d_in[2];
    const float* Wb  = (const float*)d_in[5];
    const float* bb  = (const float*)d_in[6];
    const float* Wk  = (const float*)d_in[7];
    const float* Wq  = (const float*)d_in[8];
    const float* We  = (const float*)d_in[9];
    const float* Wih = (const float*)d_in[10];
    const float* Whh = (const float*)d_in[11];
    const float* bih = (const float*)d_in[12];
    const float* bhh = (const float*)d_in[13];
    const float* Wpre= (const float*)d_in[14];

    char* ws = (char*)d_ws;
    if (ws_size < 272236544UL) return;   // loud failure (output stays poisoned)
    float*          h0f   = (float*)(ws + 0);                  // 64*1024*4
    float*          hp    = (float*)(ws + 262144);             // 64*4096*4
    unsigned short* hbf   = (unsigned short*)(ws + 1310720);   // 64*1024*2 (h0 only)
    unsigned short* efb   = (unsigned short*)(ws + 1441792);   // 64*2048*2 (init only)
    int*            syncb = (int*)(ws + 1441792 + 65536);      // per-bq barriers + batch counters
    float*          scb   = (float*)(ws + 1572864);            // 64*128*4 score exchange
    unsigned short* ehb   = (unsigned short*)(ws + 1703936);   // B*S*2048*2
    unsigned short* pkb   = (unsigned short*)(ws + 35258368);  // B*S*1024*2
    unsigned short* preC  = (unsigned short*)(ws + 52035584);  // B*T*4096*2
    float*          gix   = (float*)(ws + 119144448);          // B*T*3072*4
    unsigned short* wbb   = (unsigned short*)(ws + 219807744); // 1024*2048*2
    unsigned short* wkb   = (unsigned short*)(ws + 224002048); // 1024*2048*2
    unsigned short* whpb  = (unsigned short*)(ws + 228196352); // 4096*1024*2  [Wq; Whh]
    unsigned short* wihb  = (unsigned short*)(ws + 236584960); // 3072*3072*2
    unsigned short* wpreb = (unsigned short*)(ws + 255459328); // 2048*4096*2

    float* o_states = (float*)d_out;                 // (B,T,H)
    float* o_hf     = o_states + (long)B_ * T_ * H_; // (1,B,H)
    float* o_pre    = o_hf + (long)B_ * H_;          // (B,T,2H)

    auto cvt = [&](const float* s, unsigned short* d, long n) {
        k_cvt<<<dim3((unsigned)((n / 4 + 255) / 256)), 256, 0, stream>>>(s, d, n);
    };
    cvt(eh,  ehb,  (long)B_ * S_ * 2048);
    cvt(ef,  efb,  (long)B_ * 2048);
    cvt(Wb,  wbb,  1024L * 2048);
    cvt(Wk,  wkb,  1024L * 2048);
    cvt(Wq,  whpb, 1024L * 1024);
    cvt(Whh, whpb + 1024L * 1024, 3072L * 1024);
    cvt(Wih, wihb, 3072L * 3072);
    cvt(Wpre,wpreb,2048L * 4096);
    k_cvt_te<<<8192, 256, 0, stream>>>(te, preC, (long)B_ * T_ * 1024);

    // h0 = tanh(encoder_final @ W_bridge^T + b_bridge)  (consumes efb; hp = scratch)
    k_gemm<0><<<dim3(16, 1), 256, 0, stream>>>(efb, 2048, wbb, 2048, hp, 1024, 2048);
    k_h0act<<<256, 256, 0, stream>>>(hp, bb, h0f, hbf);
    // reset barrier vars + per-batch counters (stream-ordered, deterministic per call)
    (void)hipMemsetAsync(syncb, 0, 65536, stream);
    // proj_key = encoder_hidden @ W_key^T  (bf16 out): M=8192, N=1024, K=2048
    k_gemm128<1><<<dim3(8, 64), 256, 0, stream>>>(ehb, 2048, wkb, 2048, pkb, 1024, 2048);
    // gi_x = trg_embed @ W_ih[:, :E]^T  (f32 out): M=8192, N=3072, K=1024
    k_gemm128<0><<<dim3(24, 64), 256, 0, stream>>>(preC, 4096, wihb, 3072, gix, 3072, 1024);

    // persistent step loop: 4 independent 64-block bq pipelines, eh pinned in LDS
    k_steps<<<NBLK, 1024, 0, stream>>>(pkb, ehb, whpb, wihb, We, gix, bih, bhh,
                                       h0f, hbf, hp, preC, o_states, o_hf, syncb, scb);

    // pre_output = [x_t, h_t, ctx_t] @ W_pre^T: M=8192, N=2048, K=4096
    k_gemm128<0><<<dim3(16, 64), 256, 0, stream>>>(preC, 4096, wpreb, 4096, o_pre, 2048, 4096);
}

// Round 21
// 5057.450 us; speedup vs baseline: 1.3051x; 1.0088x over previous
//
#include <hip/hip_runtime.h>
#include <hip/hip_bf16.h>

// ---------- types ----------
typedef short    bf16x8 __attribute__((ext_vector_type(8)));   // 8 bf16 (4 VGPRs), MFMA A/B frag
typedef float    f32x4  __attribute__((ext_vector_type(4)));   // MFMA C/D frag
typedef unsigned short u16x8 __attribute__((ext_vector_type(8)));

#define B_  64
#define S_  128
#define T_  128
#define E_  1024
#define H_  1024
#define NBLK 256

#define RLX __ATOMIC_RELAXED
#define AGT __HIP_MEMORY_SCOPE_AGENT

__device__ __forceinline__ unsigned short f2bf(float f) {
    unsigned u = __float_as_uint(f);
    unsigned r = (u + 0x7FFFu + ((u >> 16) & 1u)) >> 16;   // RNE
    return (unsigned short)r;
}
__device__ __forceinline__ float bf2f(unsigned short u) {
    return __uint_as_float((unsigned)u << 16);
}
__device__ __forceinline__ float my_tanh(float x) {
    float e = __expf(2.0f * x);
    return 1.0f - 2.0f / (e + 1.0f);
}
__device__ __forceinline__ float my_sig(float x) {
    return 1.0f / (1.0f + __expf(-x));
}

// ---------- coherent (L2-bypass) relaxed accessors ----------
__device__ __forceinline__ void st8c(void* p, unsigned long long v) {
    __hip_atomic_store((unsigned long long*)p, v, RLX, AGT);
}
__device__ __forceinline__ unsigned long long ld8c(const void* p) {
    return __hip_atomic_load((const unsigned long long*)p, RLX, AGT);
}
__device__ __forceinline__ void st4c(void* p, unsigned v) {
    __hip_atomic_store((unsigned*)p, v, RLX, AGT);
}
__device__ __forceinline__ void st4f(void* p, float v) {
    __hip_atomic_store((float*)p, v, RLX, AGT);
}
__device__ __forceinline__ float ld4f(const void* p) {
    return __hip_atomic_load((const float*)p, RLX, AGT);
}

// ---------- per-batch-quarter barrier: 64 blocks = 8 leaves x 8, relaxed atomics ----------
__device__ __forceinline__ void gbarq(int* s, int leaf, int ord) {
    __syncthreads();                         // drains vmcnt -> sc1 stores at coherence point
    if (threadIdx.x == 0) {
        int* lc = s + 64 + leaf * 64;
        int* lg = lc + 32;
        if (__hip_atomic_fetch_add(lc, 1, RLX, AGT) == 8 * ord - 1) {
            if (__hip_atomic_fetch_add(s, 1, RLX, AGT) == 8 * ord - 1) {
                __hip_atomic_store(s + 32, ord, RLX, AGT);
            } else {
                while (__hip_atomic_load(s + 32, RLX, AGT) < ord)
                    __builtin_amdgcn_s_sleep(2);
            }
            __hip_atomic_store(lg, ord, RLX, AGT);
        } else {
            while (__hip_atomic_load(lg, RLX, AGT) < ord)
                __builtin_amdgcn_s_sleep(2);
        }
    }
    __syncthreads();
}

// ---------- async global->LDS (16B per lane; LDS dest = wave base + lane*16) ----------
__device__ __forceinline__ void gld_lds16(const void* g, void* l) {
    __builtin_amdgcn_global_load_lds(
        (const __attribute__((address_space(1))) unsigned int*)(unsigned long long)g,
        (__attribute__((address_space(3))) unsigned int*)(unsigned int)(unsigned long long)l,
        16, 0, 0);
}

// ---------- f32 -> bf16 conversion ----------
__global__ void k_cvt(const float* __restrict__ s, unsigned short* __restrict__ d, long n) {
    long i = ((long)blockIdx.x * blockDim.x + threadIdx.x) * 4;
    if (i >= n) return;
    float4 f = *(const float4*)(s + i);
    ushort4 o;
    o.x = f2bf(f.x); o.y = f2bf(f.y); o.z = f2bf(f.z); o.w = f2bf(f.w);
    *(ushort4*)(d + i) = o;
}

// trg_embed (B,T,1024) -> preC[(b*T+t)*4096 + 0..1023]
__global__ void k_cvt_te(const float* __restrict__ s, unsigned short* __restrict__ d, long n) {
    long i = ((long)blockIdx.x * blockDim.x + threadIdx.x) * 4;
    if (i >= n) return;
    float4 f = *(const float4*)(s + i);
    long row = i >> 10, col = i & 1023;
    ushort4 o;
    o.x = f2bf(f.x); o.y = f2bf(f.y); o.z = f2bf(f.z); o.w = f2bf(f.w);
    *(ushort4*)(d + row * 4096 + col) = o;
}

// ---------- small MFMA GEMM (h0 only): C[M,N] = A[M,K] @ W[N,K]^T ----------
template<int OUTBF>
__global__ __launch_bounds__(256) void k_gemm(const unsigned short* __restrict__ A, long lda,
                                              const unsigned short* __restrict__ W, long ldw,
                                              void* __restrict__ Cv, long ldc, int K) {
    const int lane = threadIdx.x & 63;
    const int wv   = threadIdx.x >> 6;
    const int r    = lane & 15, g = lane >> 4;
    const long m0  = (long)blockIdx.y * 64 + wv * 16;
    const long n0  = (long)blockIdx.x * 64;
    const unsigned short* a  = A + (m0 + r) * lda + g * 8;
    const unsigned short* w0 = W + (n0 + r) * ldw + g * 8;
    f32x4 acc[4] = {};
    for (int k = 0; k < K; k += 32) {
        bf16x8 av = *(const bf16x8*)(a + k);
#pragma unroll
        for (int j = 0; j < 4; ++j) {
            bf16x8 bv = *(const bf16x8*)(w0 + (long)j * 16 * ldw + k);
            acc[j] = __builtin_amdgcn_mfma_f32_16x16x32_bf16(av, bv, acc[j], 0, 0, 0);
        }
    }
#pragma unroll
    for (int j = 0; j < 4; ++j) {
        long row = m0 + g * 4;
        long col = n0 + j * 16 + r;
#pragma unroll
        for (int rr = 0; rr < 4; ++rr) {
            float v = acc[j][rr];
            if (OUTBF) ((unsigned short*)Cv)[(row + rr) * ldc + col] = f2bf(v);
            else       ((float*)Cv)[(row + rr) * ldc + col] = v;
        }
    }
}

// ---------- m97-style 128x128 GEMM: global_load_lds staging, 4 waves (2x2), BK=64 ----------
// K % 64 == 0. Halved barrier count vs BK=32.
template<int OUTBF>
__global__ __launch_bounds__(256) void k_gemm128(const unsigned short* __restrict__ A, long lda,
                                                 const unsigned short* __restrict__ W, long ldw,
                                                 void* __restrict__ Cv, long ldc, int K) {
    __shared__ unsigned short lA[128 * 64];
    __shared__ unsigned short lB[128 * 64];
    const int tid  = threadIdx.x;
    const int lane = tid & 63, wv = tid >> 6;
    const int r = lane & 15, gg = lane >> 4;
    const int wm = (wv >> 1) * 64, wn = (wv & 1) * 64;
    const long m0 = (long)blockIdx.y * 128;
    const long n0 = (long)blockIdx.x * 128;
    // staging: 16 chunks/matrix; chunk ci = rows [8ci, 8ci+8) x 64 cols; wave wv owns ci = 4wv..4wv+3
    // lane l -> row 8ci + (l>>3), col short (l&7)*8; LDS offset = ci*512 shorts + l*8 shorts (linear)
    const int rl = lane >> 3, cl = (lane & 7) * 8;
    f32x4 acc[4][4] = {};
    for (int k0 = 0; k0 < K; k0 += 64) {
        __syncthreads();                     // previous compute done before overwrite
#pragma unroll
        for (int i = 0; i < 4; ++i) {
            const int ci = wv * 4 + i;
            gld_lds16(A + (m0 + 8 * ci + rl) * lda + cl + k0, &lA[ci * 512]);
            gld_lds16(W + (n0 + 8 * ci + rl) * ldw + cl + k0, &lB[ci * 512]);
        }
        __syncthreads();                     // staging complete (vmcnt drained)
#pragma unroll
        for (int kk = 0; kk < 64; kk += 32) {
            bf16x8 av[4], bv[4];
#pragma unroll
            for (int i = 0; i < 4; ++i) {
                av[i] = *(const bf16x8*)&lA[(wm + i * 16 + r) * 64 + kk + gg * 8];
                bv[i] = *(const bf16x8*)&lB[(wn + i * 16 + r) * 64 + kk + gg * 8];
            }
#pragma unroll
            for (int mi = 0; mi < 4; ++mi)
#pragma unroll
                for (int ni = 0; ni < 4; ++ni)
                    acc[mi][ni] = __builtin_amdgcn_mfma_f32_16x16x32_bf16(av[mi], bv[ni], acc[mi][ni], 0, 0, 0);
        }
    }
#pragma unroll
    for (int mi = 0; mi < 4; ++mi) {
#pragma unroll
        for (int ni = 0; ni < 4; ++ni) {
            const long col = n0 + wn + ni * 16 + r;
#pragma unroll
            for (int rr = 0; rr < 4; ++rr) {
                const long row = m0 + wm + mi * 16 + gg * 4 + rr;
                float v = acc[mi][ni][rr];
                if (OUTBF) ((unsigned short*)Cv)[row * ldc + col] = f2bf(v);
                else       ((float*)Cv)[row * ldc + col] = v;
            }
        }
    }
}

// ---------- h0 activation ----------
__global__ void k_h0act(const float* __restrict__ hp, const float* __restrict__ bb,
                        float* __restrict__ h, unsigned short* __restrict__ hbf) {
    int i = blockIdx.x * 256 + threadIdx.x;   // 65536
    float v = my_tanh(hp[i] + bb[i & 1023]);
    h[i] = v; hbf[i] = f2bf(v);
}

// ---------- persistent step loop: 4 INDEPENDENT 64-block batch-quarter pipelines ----------
// Round-20 structure; P2 q staged once through LDS (16x less coherent q traffic).
__global__ __launch_bounds__(1024) void k_steps(
        const unsigned short* __restrict__ pk, const unsigned short* __restrict__ eh,
        const unsigned short* __restrict__ whp, const unsigned short* __restrict__ wih,
        const float* __restrict__ We, const float* __restrict__ gix,
        const float* __restrict__ bih, const float* __restrict__ bhh,
        const float* __restrict__ h0f, const unsigned short* __restrict__ hbf,
        float* __restrict__ hp, unsigned short* __restrict__ preC,
        float* __restrict__ o_states, float* __restrict__ o_hf,
        int* __restrict__ sync, float* __restrict__ scb) {
    __shared__ unsigned short ehs[S_ * 512];  // 128 KB: eh[p2_b][:, q4*512 .. +512) resident
    __shared__ float smf[16 * 64 * 4];        // 16 KB, reused per phase
    __shared__ float qsm[16 * 66];            // q transposed+padded: q[n] at [(n%16)*66 + n/16]
    __shared__ unsigned short hsm[256];
    const int g    = blockIdx.x;
    const int tid  = threadIdx.x;
    const int wv   = tid >> 6, lane = tid & 63;
    const int r    = lane & 15, gg = lane >> 4;

    // ---- bq-aligned roles: bq = g>>6, z = g&63, xcd = z&7, sub = z>>3 ----
    const int bq  = g >> 6, z = g & 63;
    const int xcd = z & 7, sub = z >> 3;
    int* bqs = sync + bq * 1024;                          // this bq's barrier region
    const int p1_cb = xcd * 8 + sub;                      // 64-col tile 0..63 (8 per XCD)
    const int p1_ct = wv & 3, p1_ks = wv >> 2;
    const int p2_b  = bq * 16 + xcd * 2 + (sub & 1);
    const int p2_q4 = sub >> 1;
    const int jt = xcd * 8 + sub;
    const int j0 = jt * 16, b0 = bq * 16;
    const int lr = tid >> 4, lc = tid & 15;
    float hreg = (tid < 256) ? h0f[(long)(b0 + lr) * 1024 + j0 + lc] : 0.f;

    // ---- one-time: stage this block's eh slice into LDS (128 rows x 512 cols bf16) ----
    {
        const unsigned short* src = eh + (long)p2_b * S_ * 2048 + p2_q4 * 512;
#pragma unroll
        for (int it = 0; it < 8; ++it) {
            int i = it * 1024 + tid;              // 8192 chunks of 8 ushorts
            int row = i >> 6, c8i = (i & 63) * 8;
            *(u16x8*)&ehs[row * 512 + c8i] = *(const u16x8*)(src + (long)row * 2048 + c8i);
        }
    }
    __syncthreads();

    int ord = 0;

#pragma unroll 1
    for (int t = 0; t < T_; ++t) {
        // ======== P1: hp[bq rows, 4096] = h_{t-1} @ whp^T ; 16 rows x 64 cols per block ====
        {
            const int n0 = p1_cb * 64 + p1_ct * 16;
            const int k0 = p1_ks * 256;
            const int b  = bq * 16 + r;
            const unsigned short* arow = (t == 0)
                ? hbf + (long)b * 1024 + k0 + gg * 8
                : preC + ((long)b * T_ + (t - 1)) * 4096 + 1024 + k0 + gg * 8;   // plain
            const unsigned short* bw = whp + (long)(n0 + r) * 1024 + k0 + gg * 8;
            f32x4 acc = {};
#pragma unroll
            for (int k = 0; k < 256; k += 32) {
                bf16x8 av = *(const bf16x8*)(arow + k);
                bf16x8 bv = *(const bf16x8*)(bw + k);
                acc = __builtin_amdgcn_mfma_f32_16x16x32_bf16(av, bv, acc, 0, 0, 0);
            }
            *(f32x4*)&smf[(wv * 64 + lane) * 4] = acc;
            __syncthreads();
            if (p1_ks == 0) {   // wv == p1_ct
                f32x4 s0 = *(f32x4*)&smf[((0 * 4 + p1_ct) * 64 + lane) * 4];
                f32x4 s1 = *(f32x4*)&smf[((1 * 4 + p1_ct) * 64 + lane) * 4];
                f32x4 s2 = *(f32x4*)&smf[((2 * 4 + p1_ct) * 64 + lane) * 4];
                f32x4 s3 = *(f32x4*)&smf[((3 * 4 + p1_ct) * 64 + lane) * 4];
                f32x4 s = s0 + s1 + s2 + s3;
#pragma unroll
                for (int rr = 0; rr < 4; ++rr)
                    st4f(&hp[(long)(bq * 16 + gg * 4 + rr) * 4096 + n0 + r], s[rr]);
            }
        }
        gbarq(bqs, xcd, ++ord);

        // ======== P2: attention; q staged via LDS; energy dedup'd + sc1 exchange ========
        {
            const int b = p2_b;
            // --- stage q[b] (4 KB) into LDS once: 256 threads x 16B coherent reads ---
            if (tid < 256) {
                unsigned long long u0 = ld8c(hp + (long)b * 4096 + tid * 4);
                unsigned long long u1 = ld8c(hp + (long)b * 4096 + tid * 4 + 2);
                const int col = tid >> 2, rowb = 4 * (tid & 3);
                qsm[(rowb + 0) * 66 + col] = __uint_as_float((unsigned)u0);
                qsm[(rowb + 1) * 66 + col] = __uint_as_float((unsigned)(u0 >> 32));
                qsm[(rowb + 2) * 66 + col] = __uint_as_float((unsigned)u1);
                qsm[(rowb + 3) * 66 + col] = __uint_as_float((unsigned)(u1 >> 32));
            }
            __syncthreads();
            // --- energy: wave wv computes scores s = q4*32 + wv*2 + {0,1}; lane: 16 h ---
            const int hh = lane * 16;
            float q[16], w16[16];
#pragma unroll
            for (int i = 0; i < 16; ++i) {
                q[i]   = qsm[i * 66 + lane];     // conflict-free: consecutive lanes adjacent
                w16[i] = We[hh + i];
            }
#pragma unroll
            for (int k2 = 0; k2 < 2; ++k2) {
                const int s = p2_q4 * 32 + wv * 2 + k2;
                const unsigned short* row = pk + ((long)b * S_ + s) * 1024 + hh;
                u16x8 v0 = *(const u16x8*)(row);
                u16x8 v1 = *(const u16x8*)(row + 8);
                float acc = 0.f;
#pragma unroll
                for (int i = 0; i < 8; ++i) acc += my_tanh(q[i] + bf2f(v0[i])) * w16[i];
#pragma unroll
                for (int i = 0; i < 8; ++i) acc += my_tanh(q[8 + i] + bf2f(v1[i])) * w16[8 + i];
#pragma unroll
                for (int off = 32; off; off >>= 1) acc += __shfl_xor(acc, off);
                if (lane == 0) st4f(&scb[b * 128 + s], acc);
            }
            // --- 4-block mini-barrier (per-batch monotonic counter) ---
            __syncthreads();                 // drains vmcnt: score stores at coherence point
            if (tid == 0) {
                int* bc = sync + 4096 + b * 32;
                __hip_atomic_fetch_add(bc, 1, RLX, AGT);
                while (__hip_atomic_load(bc, RLX, AGT) < 4 * (t + 1))
                    __builtin_amdgcn_s_sleep(2);
            }
            __syncthreads();
            // --- softmax over 128 (threads 0..127), scores from scb (sc1) ---
            float* red = &smf[648];
            float e = 0.f, sc = 0.f;
            if (tid < 128) {
                sc = ld4f(&scb[b * 128 + tid]);
                float m = sc;
#pragma unroll
                for (int off = 32; off; off >>= 1) m = fmaxf(m, __shfl_xor(m, off));
                if ((tid & 63) == 0) red[tid >> 6] = m;
            }
            __syncthreads();
            if (tid < 128) {
                float M = fmaxf(red[0], red[1]);
                e = __expf(sc - M);
                float s = e;
#pragma unroll
                for (int off = 32; off; off >>= 1) s += __shfl_xor(s, off);
                if ((tid & 63) == 0) red[2 + (tid >> 6)] = s;
            }
            __syncthreads();
            if (tid < 128) smf[512 + tid] = e / (red[2] + red[3]);
            __syncthreads();
            // --- context: thread = (col-pair cp, s-segment sseg of 32); LDS source ---
            const int cp = tid & 255, sseg = tid >> 8;
            const unsigned short* ehp = ehs + (sseg * 32) * 512 + cp * 2;
            float a0 = 0.f, a1 = 0.f;
#pragma unroll 4
            for (int s2 = 0; s2 < 32; ++s2) {
                float alv = smf[512 + sseg * 32 + s2];
                ushort2 v = *(const ushort2*)(ehp + s2 * 512);
                a0 += alv * bf2f(v.x); a1 += alv * bf2f(v.y);
            }
            smf[1024 + (sseg * 256 + cp) * 2]     = a0;
            smf[1024 + (sseg * 256 + cp) * 2 + 1] = a1;
            __syncthreads();
            if (tid < 256) {
                float b0s = smf[1024 + tid * 2]         + smf[1024 + (256 + tid) * 2]
                          + smf[1024 + (512 + tid) * 2] + smf[1024 + (768 + tid) * 2];
                float b1s = smf[1024 + tid * 2 + 1]         + smf[1024 + (256 + tid) * 2 + 1]
                          + smf[1024 + (512 + tid) * 2 + 1] + smf[1024 + (768 + tid) * 2 + 1];
                unsigned pack = (unsigned)f2bf(b0s) | ((unsigned)f2bf(b1s) << 16);
                st4c(preC + ((long)b * T_ + t) * 4096 + 2048 + p2_q4 * 512 + tid * 2, pack);
            }
        }
        gbarq(bqs, xcd, ++ord);

        // ======== P3: gi_ctx MFMA + GRU gates; wave = (gate, k-slice of 512) ========
        {
            if (wv < 12) {
                const int c = wv >> 2, ks = wv & 3, k0 = ks * 512;
                const unsigned short* ar = preC + ((long)(b0 + r) * T_ + t) * 4096 + 2048 + k0 + gg * 8; // plain
                const unsigned short* bw = wih + ((long)(c * 1024 + j0 + r)) * 3072 + 1024 + k0 + gg * 8;
                f32x4 acc = {};
#pragma unroll
                for (int k = 0; k < 512; k += 32) {
                    bf16x8 av = *(const bf16x8*)(ar + k);
                    bf16x8 bv = *(const bf16x8*)(bw + k);
                    acc = __builtin_amdgcn_mfma_f32_16x16x32_bf16(av, bv, acc, 0, 0, 0);
                }
                *(f32x4*)&smf[(wv * 64 + lane) * 4] = acc;
            }
            __syncthreads();
            if (tid < 256) {
                const int lane_ = (lr >> 2) * 16 + lc, rr_ = lr & 3;
                float gi[3];
#pragma unroll
                for (int c = 0; c < 3; ++c) {
                    gi[c] = smf[((c * 4 + 0) * 64 + lane_) * 4 + rr_]
                          + smf[((c * 4 + 1) * 64 + lane_) * 4 + rr_]
                          + smf[((c * 4 + 2) * 64 + lane_) * 4 + rr_]
                          + smf[((c * 4 + 3) * 64 + lane_) * 4 + rr_];
                }
                const int b = b0 + lr, j = j0 + lc;
                const long bt = (long)b * T_ + t;
                float ghr = ld4f(&hp[(long)b * 4096 + 1024 + j]);
                float ghz = ld4f(&hp[(long)b * 4096 + 2048 + j]);
                float ghn = ld4f(&hp[(long)b * 4096 + 3072 + j]);
                float grv = gix[bt * 3072 + j]        + gi[0] + bih[j]        + ghr + bhh[j];
                float gzv = gix[bt * 3072 + 1024 + j] + gi[1] + bih[1024 + j] + ghz + bhh[1024 + j];
                float gni = gix[bt * 3072 + 2048 + j] + gi[2] + bih[2048 + j];
                float ghn2 = ghn + bhh[2048 + j];
                float rg = my_sig(grv);
                float zg = my_sig(gzv);
                float nv = my_tanh(gni + rg * ghn2);
                float hn = (1.f - zg) * nv + zg * hreg;
                hreg = hn;
                unsigned short hb16 = f2bf(hn);
                o_states[bt * 1024 + j] = hn;                    // plain (read after kernel)
                if (t == T_ - 1) o_hf[(long)b * 1024 + j] = hn;  // plain
                hsm[tid] = hb16;
            }
            __syncthreads();
            // pack h_t -> preC h-slot (sc1; next-step P1 reads plain)
            if (tid < 64) {
                const int plr = tid >> 2, pc4 = (tid & 3) * 4;
                unsigned long long v =
                      (unsigned long long)hsm[plr * 16 + pc4]
                    | ((unsigned long long)hsm[plr * 16 + pc4 + 1] << 16)
                    | ((unsigned long long)hsm[plr * 16 + pc4 + 2] << 32)
                    | ((unsigned long long)hsm[plr * 16 + pc4 + 3] << 48);
                st8c(preC + ((long)(b0 + plr) * T_ + t) * 4096 + 1024 + j0 + pc4, v);
            }
        }
        gbarq(bqs, xcd, ++ord);
    }
}

// ---------- host ----------
extern "C" void kernel_launch(void* const* d_in, const int* in_sizes, int n_in,
                              void* d_out, int out_size, void* d_ws, size_t ws_size,
                              hipStream_t stream) {
    const float* te  = (const float*)d_in[0];
    const float* eh  = (const float*)d_in[1];
    const float* ef  = (const float*)d_in[2];
    const float* Wb  = (const float*)d_in[5];
    const float* bb  = (const float*)d_in[6];
    const float* Wk  = (const float*)d_in[7];
    const float* Wq  = (const float*)d_in[8];
    const float* We  = (const float*)d_in[9];
    const float* Wih = (const float*)d_in[10];
    const float* Whh = (const float*)d_in[11];
    const float* bih = (const float*)d_in[12];
    const float* bhh = (const float*)d_in[13];
    const float* Wpre= (const float*)d_in[14];

    char* ws = (char*)d_ws;
    if (ws_size < 272236544UL) return;   // loud failure (output stays poisoned)
    float*          h0f   = (float*)(ws + 0);                  // 64*1024*4
    float*          hp    = (float*)(ws + 262144);             // 64*4096*4
    unsigned short* hbf   = (unsigned short*)(ws + 1310720);   // 64*1024*2 (h0 only)
    unsigned short* efb   = (unsigned short*)(ws + 1441792);   // 64*2048*2 (init only)
    int*            syncb = (int*)(ws + 1441792 + 65536);      // per-bq barriers + batch counters
    float*          scb   = (float*)(ws + 1572864);            // 64*128*4 score exchange
    unsigned short* ehb   = (unsigned short*)(ws + 1703936);   // B*S*2048*2
    unsigned short* pkb   = (unsigned short*)(ws + 35258368);  // B*S*1024*2
    unsigned short* preC  = (unsigned short*)(ws + 52035584);  // B*T*4096*2
    float*          gix   = (float*)(ws + 119144448);          // B*T*3072*4
    unsigned short* wbb   = (unsigned short*)(ws + 219807744); // 1024*2048*2
    unsigned short* wkb   = (unsigned short*)(ws + 224002048); // 1024*2048*2
    unsigned short* whpb  = (unsigned short*)(ws + 228196352); // 4096*1024*2  [Wq; Whh]
    unsigned short* wihb  = (unsigned short*)(ws + 236584960); // 3072*3072*2
    unsigned short* wpreb = (unsigned short*)(ws + 255459328); // 2048*4096*2

    float* o_states = (float*)d_out;                 // (B,T,H)
    float* o_hf     = o_states + (long)B_ * T_ * H_; // (1,B,H)
    float* o_pre    = o_hf + (long)B_ * H_;          // (B,T,2H)

    auto cvt = [&](const float* s, unsigned short* d, long n) {
        k_cvt<<<dim3((unsigned)((n / 4 + 255) / 256)), 256, 0, stream>>>(s, d, n);
    };
    cvt(eh,  ehb,  (long)B_ * S_ * 2048);
    cvt(ef,  efb,  (long)B_ * 2048);
    cvt(Wb,  wbb,  1024L * 2048);
    cvt(Wk,  wkb,  1024L * 2048);
    cvt(Wq,  whpb, 1024L * 1024);
    cvt(Whh, whpb + 1024L * 1024, 3072L * 1024);
    cvt(Wih, wihb, 3072L * 3072);
    cvt(Wpre,wpreb,2048L * 4096);
    k_cvt_te<<<8192, 256, 0, stream>>>(te, preC, (long)B_ * T_ * 1024);

    // h0 = tanh(encoder_final @ W_bridge^T + b_bridge)  (consumes efb; hp = scratch)
    k_gemm<0><<<dim3(16, 1), 256, 0, stream>>>(efb, 2048, wbb, 2048, hp, 1024, 2048);
    k_h0act<<<256, 256, 0, stream>>>(hp, bb, h0f, hbf);
    // reset barrier vars + per-batch counters (stream-ordered, deterministic per call)
    (void)hipMemsetAsync(syncb, 0, 65536, stream);
    // proj_key = encoder_hidden @ W_key^T  (bf16 out): M=8192, N=1024, K=2048
    k_gemm128<1><<<dim3(8, 64), 256, 0, stream>>>(ehb, 2048, wkb, 2048, pkb, 1024, 2048);
    // gi_x = trg_embed @ W_ih[:, :E]^T  (f32 out): M=8192, N=3072, K=1024
    k_gemm128<0><<<dim3(24, 64), 256, 0, stream>>>(preC, 4096, wihb, 3072, gix, 3072, 1024);

    // persistent step loop: 4 independent 64-block bq pipelines, eh pinned in LDS
    k_steps<<<NBLK, 1024, 0, stream>>>(pkb, ehb, whpb, wihb, We, gix, bih, bhh,
                                       h0f, hbf, hp, preC, o_states, o_hf, syncb, scb);

    // pre_output = [x_t, h_t, ctx_t] @ W_pre^T: M=8192, N=2048, K=4096
    k_gemm128<0><<<dim3(16, 64), 256, 0, stream>>>(preC, 4096, wpreb, 4096, o_pre, 2048, 4096);
}

// Round 22
// 4941.972 us; speedup vs baseline: 1.3356x; 1.0234x over previous
//
#include <hip/hip_runtime.h>
#include <hip/hip_bf16.h>

// ---------- types ----------
typedef short    bf16x8 __attribute__((ext_vector_type(8)));   // 8 bf16 (4 VGPRs), MFMA A/B frag
typedef float    f32x4  __attribute__((ext_vector_type(4)));   // MFMA C/D frag
typedef unsigned short u16x8 __attribute__((ext_vector_type(8)));

#define B_  64
#define S_  128
#define T_  128
#define E_  1024
#define H_  1024
#define NBLK 256

#define RLX __ATOMIC_RELAXED
#define AGT __HIP_MEMORY_SCOPE_AGENT

__device__ __forceinline__ unsigned short f2bf(float f) {
    unsigned u = __float_as_uint(f);
    unsigned r = (u + 0x7FFFu + ((u >> 16) & 1u)) >> 16;   // RNE
    return (unsigned short)r;
}
__device__ __forceinline__ float bf2f(unsigned short u) {
    return __uint_as_float((unsigned)u << 16);
}
__device__ __forceinline__ float my_tanh(float x) {
    float e = __expf(2.0f * x);
    return 1.0f - 2.0f / (e + 1.0f);
}
__device__ __forceinline__ float my_sig(float x) {
    return 1.0f / (1.0f + __expf(-x));
}

// ---------- coherent (L2-bypass) relaxed accessors ----------
__device__ __forceinline__ void st8c(void* p, unsigned long long v) {
    __hip_atomic_store((unsigned long long*)p, v, RLX, AGT);
}
__device__ __forceinline__ unsigned long long ld8c(const void* p) {
    return __hip_atomic_load((const unsigned long long*)p, RLX, AGT);
}
__device__ __forceinline__ void st4c(void* p, unsigned v) {
    __hip_atomic_store((unsigned*)p, v, RLX, AGT);
}
__device__ __forceinline__ void st4f(void* p, float v) {
    __hip_atomic_store((float*)p, v, RLX, AGT);
}
__device__ __forceinline__ float ld4f(const void* p) {
    return __hip_atomic_load((const float*)p, RLX, AGT);
}

// ---------- per-batch-quarter barrier: 64 blocks = 8 leaves x 8, relaxed atomics ----------
__device__ __forceinline__ void gbarq(int* s, int leaf, int ord) {
    __syncthreads();                         // drains vmcnt -> sc1 stores at coherence point
    if (threadIdx.x == 0) {
        int* lc = s + 64 + leaf * 64;
        int* lg = lc + 32;
        if (__hip_atomic_fetch_add(lc, 1, RLX, AGT) == 8 * ord - 1) {
            if (__hip_atomic_fetch_add(s, 1, RLX, AGT) == 8 * ord - 1) {
                __hip_atomic_store(s + 32, ord, RLX, AGT);
            } else {
                while (__hip_atomic_load(s + 32, RLX, AGT) < ord)
                    __builtin_amdgcn_s_sleep(2);
            }
            __hip_atomic_store(lg, ord, RLX, AGT);
        } else {
            while (__hip_atomic_load(lg, RLX, AGT) < ord)
                __builtin_amdgcn_s_sleep(2);
        }
    }
    __syncthreads();
}

// ---------- async global->LDS (16B per lane; LDS dest = wave base + lane*16) ----------
__device__ __forceinline__ void gld_lds16(const void* g, void* l) {
    __builtin_amdgcn_global_load_lds(
        (const __attribute__((address_space(1))) unsigned int*)(unsigned long long)g,
        (__attribute__((address_space(3))) unsigned int*)(unsigned int)(unsigned long long)l,
        16, 0, 0);
}

// ---------- f32 -> bf16 conversion ----------
__global__ void k_cvt(const float* __restrict__ s, unsigned short* __restrict__ d, long n) {
    long i = ((long)blockIdx.x * blockDim.x + threadIdx.x) * 4;
    if (i >= n) return;
    float4 f = *(const float4*)(s + i);
    ushort4 o;
    o.x = f2bf(f.x); o.y = f2bf(f.y); o.z = f2bf(f.z); o.w = f2bf(f.w);
    *(ushort4*)(d + i) = o;
}

// trg_embed (B,T,1024) -> preC[(b*T+t)*4096 + 0..1023]
__global__ void k_cvt_te(const float* __restrict__ s, unsigned short* __restrict__ d, long n) {
    long i = ((long)blockIdx.x * blockDim.x + threadIdx.x) * 4;
    if (i >= n) return;
    float4 f = *(const float4*)(s + i);
    long row = i >> 10, col = i & 1023;
    ushort4 o;
    o.x = f2bf(f.x); o.y = f2bf(f.y); o.z = f2bf(f.z); o.w = f2bf(f.w);
    *(ushort4*)(d + row * 4096 + col) = o;
}

// ---------- small MFMA GEMM (h0 only): C[M,N] = A[M,K] @ W[N,K]^T ----------
template<int OUTBF>
__global__ __launch_bounds__(256) void k_gemm(const unsigned short* __restrict__ A, long lda,
                                              const unsigned short* __restrict__ W, long ldw,
                                              void* __restrict__ Cv, long ldc, int K) {
    const int lane = threadIdx.x & 63;
    const int wv   = threadIdx.x >> 6;
    const int r    = lane & 15, g = lane >> 4;
    const long m0  = (long)blockIdx.y * 64 + wv * 16;
    const long n0  = (long)blockIdx.x * 64;
    const unsigned short* a  = A + (m0 + r) * lda + g * 8;
    const unsigned short* w0 = W + (n0 + r) * ldw + g * 8;
    f32x4 acc[4] = {};
    for (int k = 0; k < K; k += 32) {
        bf16x8 av = *(const bf16x8*)(a + k);
#pragma unroll
        for (int j = 0; j < 4; ++j) {
            bf16x8 bv = *(const bf16x8*)(w0 + (long)j * 16 * ldw + k);
            acc[j] = __builtin_amdgcn_mfma_f32_16x16x32_bf16(av, bv, acc[j], 0, 0, 0);
        }
    }
#pragma unroll
    for (int j = 0; j < 4; ++j) {
        long row = m0 + g * 4;
        long col = n0 + j * 16 + r;
#pragma unroll
        for (int rr = 0; rr < 4; ++rr) {
            float v = acc[j][rr];
            if (OUTBF) ((unsigned short*)Cv)[(row + rr) * ldc + col] = f2bf(v);
            else       ((float*)Cv)[(row + rr) * ldc + col] = v;
        }
    }
}

// ---------- m97-style 128x128 GEMM: global_load_lds staging, 4 waves (2x2), BK=64 ----------
template<int OUTBF>
__global__ __launch_bounds__(256) void k_gemm128(const unsigned short* __restrict__ A, long lda,
                                                 const unsigned short* __restrict__ W, long ldw,
                                                 void* __restrict__ Cv, long ldc, int K) {
    __shared__ unsigned short lA[128 * 64];
    __shared__ unsigned short lB[128 * 64];
    const int tid  = threadIdx.x;
    const int lane = tid & 63, wv = tid >> 6;
    const int r = lane & 15, gg = lane >> 4;
    const int wm = (wv >> 1) * 64, wn = (wv & 1) * 64;
    const long m0 = (long)blockIdx.y * 128;
    const long n0 = (long)blockIdx.x * 128;
    const int rl = lane >> 3, cl = (lane & 7) * 8;
    f32x4 acc[4][4] = {};
    for (int k0 = 0; k0 < K; k0 += 64) {
        __syncthreads();
#pragma unroll
        for (int i = 0; i < 4; ++i) {
            const int ci = wv * 4 + i;
            gld_lds16(A + (m0 + 8 * ci + rl) * lda + cl + k0, &lA[ci * 512]);
            gld_lds16(W + (n0 + 8 * ci + rl) * ldw + cl + k0, &lB[ci * 512]);
        }
        __syncthreads();
#pragma unroll
        for (int kk = 0; kk < 64; kk += 32) {
            bf16x8 av[4], bv[4];
#pragma unroll
            for (int i = 0; i < 4; ++i) {
                av[i] = *(const bf16x8*)&lA[(wm + i * 16 + r) * 64 + kk + gg * 8];
                bv[i] = *(const bf16x8*)&lB[(wn + i * 16 + r) * 64 + kk + gg * 8];
            }
#pragma unroll
            for (int mi = 0; mi < 4; ++mi)
#pragma unroll
                for (int ni = 0; ni < 4; ++ni)
                    acc[mi][ni] = __builtin_amdgcn_mfma_f32_16x16x32_bf16(av[mi], bv[ni], acc[mi][ni], 0, 0, 0);
        }
    }
#pragma unroll
    for (int mi = 0; mi < 4; ++mi) {
#pragma unroll
        for (int ni = 0; ni < 4; ++ni) {
            const long col = n0 + wn + ni * 16 + r;
#pragma unroll
            for (int rr = 0; rr < 4; ++rr) {
                const long row = m0 + wm + mi * 16 + gg * 4 + rr;
                float v = acc[mi][ni][rr];
                if (OUTBF) ((unsigned short*)Cv)[row * ldc + col] = f2bf(v);
                else       ((float*)Cv)[row * ldc + col] = v;
            }
        }
    }
}

// ---------- h0 activation ----------
__global__ void k_h0act(const float* __restrict__ hp, const float* __restrict__ bb,
                        float* __restrict__ h, unsigned short* __restrict__ hbf) {
    int i = blockIdx.x * 256 + threadIdx.x;   // 65536
    float v = my_tanh(hp[i] + bb[i & 1023]);
    h[i] = v; hbf[i] = f2bf(v);
}

// ---------- persistent step loop + fused epilogue GEMM ----------
// Round-21 structure (4 independent bq pipelines, eh-in-LDS, q-via-LDS, dedup'd energy);
// after a bq's last barrier, its 64 blocks compute their slab of o_pre in-kernel
// (ehs LDS reused as GEMM staging; 16 waves = 4 quads x 4 waves, quad = one 128-col tile).
__global__ __launch_bounds__(1024) void k_steps(
        const unsigned short* __restrict__ pk, const unsigned short* __restrict__ eh,
        const unsigned short* __restrict__ whp, const unsigned short* __restrict__ wih,
        const float* __restrict__ We, const float* __restrict__ gix,
        const float* __restrict__ bih, const float* __restrict__ bhh,
        const float* __restrict__ h0f, const unsigned short* __restrict__ hbf,
        float* __restrict__ hp, unsigned short* __restrict__ preC,
        const unsigned short* __restrict__ wpre, float* __restrict__ o_pre,
        float* __restrict__ o_states, float* __restrict__ o_hf,
        int* __restrict__ sync, float* __restrict__ scb) {
    __shared__ unsigned short ehs[S_ * 512];  // 128 KB: eh slice (loop) / GEMM staging (epilogue)
    __shared__ float smf[16 * 64 * 4];        // 16 KB, reused per phase
    __shared__ float qsm[16 * 66];            // q transposed+padded
    __shared__ unsigned short hsm[256];
    const int g    = blockIdx.x;
    const int tid  = threadIdx.x;
    const int wv   = tid >> 6, lane = tid & 63;
    const int r    = lane & 15, gg = lane >> 4;

    // ---- bq-aligned roles: bq = g>>6, z = g&63, xcd = z&7, sub = z>>3 ----
    const int bq  = g >> 6, z = g & 63;
    const int xcd = z & 7, sub = z >> 3;
    int* bqs = sync + bq * 1024;                          // this bq's barrier region
    const int p1_cb = xcd * 8 + sub;
    const int p1_ct = wv & 3, p1_ks = wv >> 2;
    const int p2_b  = bq * 16 + xcd * 2 + (sub & 1);
    const int p2_q4 = sub >> 1;
    const int jt = xcd * 8 + sub;
    const int j0 = jt * 16, b0 = bq * 16;
    const int lr = tid >> 4, lc = tid & 15;
    float hreg = (tid < 256) ? h0f[(long)(b0 + lr) * 1024 + j0 + lc] : 0.f;

    // ---- one-time: stage this block's eh slice into LDS (128 rows x 512 cols bf16) ----
    {
        const unsigned short* src = eh + (long)p2_b * S_ * 2048 + p2_q4 * 512;
#pragma unroll
        for (int it = 0; it < 8; ++it) {
            int i = it * 1024 + tid;
            int row = i >> 6, c8i = (i & 63) * 8;
            *(u16x8*)&ehs[row * 512 + c8i] = *(const u16x8*)(src + (long)row * 2048 + c8i);
        }
    }
    __syncthreads();

    int ord = 0;

#pragma unroll 1
    for (int t = 0; t < T_; ++t) {
        // ======== P1: hp[bq rows, 4096] = h_{t-1} @ whp^T ========
        {
            const int n0 = p1_cb * 64 + p1_ct * 16;
            const int k0 = p1_ks * 256;
            const int b  = bq * 16 + r;
            const unsigned short* arow = (t == 0)
                ? hbf + (long)b * 1024 + k0 + gg * 8
                : preC + ((long)b * T_ + (t - 1)) * 4096 + 1024 + k0 + gg * 8;   // plain
            const unsigned short* bw = whp + (long)(n0 + r) * 1024 + k0 + gg * 8;
            f32x4 acc = {};
#pragma unroll
            for (int k = 0; k < 256; k += 32) {
                bf16x8 av = *(const bf16x8*)(arow + k);
                bf16x8 bv = *(const bf16x8*)(bw + k);
                acc = __builtin_amdgcn_mfma_f32_16x16x32_bf16(av, bv, acc, 0, 0, 0);
            }
            *(f32x4*)&smf[(wv * 64 + lane) * 4] = acc;
            __syncthreads();
            if (p1_ks == 0) {   // wv == p1_ct
                f32x4 s0 = *(f32x4*)&smf[((0 * 4 + p1_ct) * 64 + lane) * 4];
                f32x4 s1 = *(f32x4*)&smf[((1 * 4 + p1_ct) * 64 + lane) * 4];
                f32x4 s2 = *(f32x4*)&smf[((2 * 4 + p1_ct) * 64 + lane) * 4];
                f32x4 s3 = *(f32x4*)&smf[((3 * 4 + p1_ct) * 64 + lane) * 4];
                f32x4 s = s0 + s1 + s2 + s3;
#pragma unroll
                for (int rr = 0; rr < 4; ++rr)
                    st4f(&hp[(long)(bq * 16 + gg * 4 + rr) * 4096 + n0 + r], s[rr]);
            }
        }
        gbarq(bqs, xcd, ++ord);

        // ======== P2: attention; q staged via LDS; energy dedup'd + sc1 exchange ========
        {
            const int b = p2_b;
            if (tid < 256) {
                unsigned long long u0 = ld8c(hp + (long)b * 4096 + tid * 4);
                unsigned long long u1 = ld8c(hp + (long)b * 4096 + tid * 4 + 2);
                const int col = tid >> 2, rowb = 4 * (tid & 3);
                qsm[(rowb + 0) * 66 + col] = __uint_as_float((unsigned)u0);
                qsm[(rowb + 1) * 66 + col] = __uint_as_float((unsigned)(u0 >> 32));
                qsm[(rowb + 2) * 66 + col] = __uint_as_float((unsigned)u1);
                qsm[(rowb + 3) * 66 + col] = __uint_as_float((unsigned)(u1 >> 32));
            }
            __syncthreads();
            const int hh = lane * 16;
            float q[16], w16[16];
#pragma unroll
            for (int i = 0; i < 16; ++i) {
                q[i]   = qsm[i * 66 + lane];
                w16[i] = We[hh + i];
            }
#pragma unroll
            for (int k2 = 0; k2 < 2; ++k2) {
                const int s = p2_q4 * 32 + wv * 2 + k2;
                const unsigned short* row = pk + ((long)b * S_ + s) * 1024 + hh;
                u16x8 v0 = *(const u16x8*)(row);
                u16x8 v1 = *(const u16x8*)(row + 8);
                float acc = 0.f;
#pragma unroll
                for (int i = 0; i < 8; ++i) acc += my_tanh(q[i] + bf2f(v0[i])) * w16[i];
#pragma unroll
                for (int i = 0; i < 8; ++i) acc += my_tanh(q[8 + i] + bf2f(v1[i])) * w16[8 + i];
#pragma unroll
                for (int off = 32; off; off >>= 1) acc += __shfl_xor(acc, off);
                if (lane == 0) st4f(&scb[b * 128 + s], acc);
            }
            __syncthreads();
            if (tid == 0) {
                int* bc = sync + 4096 + b * 32;
                __hip_atomic_fetch_add(bc, 1, RLX, AGT);
                while (__hip_atomic_load(bc, RLX, AGT) < 4 * (t + 1))
                    __builtin_amdgcn_s_sleep(2);
            }
            __syncthreads();
            float* red = &smf[648];
            float e = 0.f, sc = 0.f;
            if (tid < 128) {
                sc = ld4f(&scb[b * 128 + tid]);
                float m = sc;
#pragma unroll
                for (int off = 32; off; off >>= 1) m = fmaxf(m, __shfl_xor(m, off));
                if ((tid & 63) == 0) red[tid >> 6] = m;
            }
            __syncthreads();
            if (tid < 128) {
                float M = fmaxf(red[0], red[1]);
                e = __expf(sc - M);
                float s = e;
#pragma unroll
                for (int off = 32; off; off >>= 1) s += __shfl_xor(s, off);
                if ((tid & 63) == 0) red[2 + (tid >> 6)] = s;
            }
            __syncthreads();
            if (tid < 128) smf[512 + tid] = e / (red[2] + red[3]);
            __syncthreads();
            const int cp = tid & 255, sseg = tid >> 8;
            const unsigned short* ehp = ehs + (sseg * 32) * 512 + cp * 2;
            float a0 = 0.f, a1 = 0.f;
#pragma unroll 4
            for (int s2 = 0; s2 < 32; ++s2) {
                float alv = smf[512 + sseg * 32 + s2];
                ushort2 v = *(const ushort2*)(ehp + s2 * 512);
                a0 += alv * bf2f(v.x); a1 += alv * bf2f(v.y);
            }
            smf[1024 + (sseg * 256 + cp) * 2]     = a0;
            smf[1024 + (sseg * 256 + cp) * 2 + 1] = a1;
            __syncthreads();
            if (tid < 256) {
                float b0s = smf[1024 + tid * 2]         + smf[1024 + (256 + tid) * 2]
                          + smf[1024 + (512 + tid) * 2] + smf[1024 + (768 + tid) * 2];
                float b1s = smf[1024 + tid * 2 + 1]         + smf[1024 + (256 + tid) * 2 + 1]
                          + smf[1024 + (512 + tid) * 2 + 1] + smf[1024 + (768 + tid) * 2 + 1];
                unsigned pack = (unsigned)f2bf(b0s) | ((unsigned)f2bf(b1s) << 16);
                st4c(preC + ((long)b * T_ + t) * 4096 + 2048 + p2_q4 * 512 + tid * 2, pack);
            }
        }
        gbarq(bqs, xcd, ++ord);

        // ======== P3: gi_ctx MFMA + GRU gates ========
        {
            if (wv < 12) {
                const int c = wv >> 2, ks = wv & 3, k0 = ks * 512;
                const unsigned short* ar = preC + ((long)(b0 + r) * T_ + t) * 4096 + 2048 + k0 + gg * 8; // plain
                const unsigned short* bw = wih + ((long)(c * 1024 + j0 + r)) * 3072 + 1024 + k0 + gg * 8;
                f32x4 acc = {};
#pragma unroll
                for (int k = 0; k < 512; k += 32) {
                    bf16x8 av = *(const bf16x8*)(ar + k);
                    bf16x8 bv = *(const bf16x8*)(bw + k);
                    acc = __builtin_amdgcn_mfma_f32_16x16x32_bf16(av, bv, acc, 0, 0, 0);
                }
                *(f32x4*)&smf[(wv * 64 + lane) * 4] = acc;
            }
            __syncthreads();
            if (tid < 256) {
                const int lane_ = (lr >> 2) * 16 + lc, rr_ = lr & 3;
                float gi[3];
#pragma unroll
                for (int c = 0; c < 3; ++c) {
                    gi[c] = smf[((c * 4 + 0) * 64 + lane_) * 4 + rr_]
                          + smf[((c * 4 + 1) * 64 + lane_) * 4 + rr_]
                          + smf[((c * 4 + 2) * 64 + lane_) * 4 + rr_]
                          + smf[((c * 4 + 3) * 64 + lane_) * 4 + rr_];
                }
                const int b = b0 + lr, j = j0 + lc;
                const long bt = (long)b * T_ + t;
                float ghr = ld4f(&hp[(long)b * 4096 + 1024 + j]);
                float ghz = ld4f(&hp[(long)b * 4096 + 2048 + j]);
                float ghn = ld4f(&hp[(long)b * 4096 + 3072 + j]);
                float grv = gix[bt * 3072 + j]        + gi[0] + bih[j]        + ghr + bhh[j];
                float gzv = gix[bt * 3072 + 1024 + j] + gi[1] + bih[1024 + j] + ghz + bhh[1024 + j];
                float gni = gix[bt * 3072 + 2048 + j] + gi[2] + bih[2048 + j];
                float ghn2 = ghn + bhh[2048 + j];
                float rg = my_sig(grv);
                float zg = my_sig(gzv);
                float nv = my_tanh(gni + rg * ghn2);
                float hn = (1.f - zg) * nv + zg * hreg;
                hreg = hn;
                unsigned short hb16 = f2bf(hn);
                o_states[bt * 1024 + j] = hn;                    // plain (read after kernel)
                if (t == T_ - 1) o_hf[(long)b * 1024 + j] = hn;  // plain
                hsm[tid] = hb16;
            }
            __syncthreads();
            if (tid < 64) {
                const int plr = tid >> 2, pc4 = (tid & 3) * 4;
                unsigned long long v =
                      (unsigned long long)hsm[plr * 16 + pc4]
                    | ((unsigned long long)hsm[plr * 16 + pc4 + 1] << 16)
                    | ((unsigned long long)hsm[plr * 16 + pc4 + 2] << 32)
                    | ((unsigned long long)hsm[plr * 16 + pc4 + 3] << 48);
                st8c(preC + ((long)(b0 + plr) * T_ + t) * 4096 + 1024 + j0 + pc4, v);
            }
        }
        gbarq(bqs, xcd, ++ord);
    }

    // ======== Fused epilogue: o_pre slab for this bq (preC rows final after last gbarq) ====
    // Block -> 128 rows x 512 cols (K=4096, BK=64). 16 waves = 4 quads; quad qd owns
    // col-tile n0e+qd*128; wave-in-quad wq covers 64x64 via 4x4 16x16 frags.
    {
        unsigned short* lA = ehs;                         // 128 x 64 bf16 (16 KB)
        const int qd = wv >> 2, wq = wv & 3;
        unsigned short* lB = ehs + 8192 + qd * 8192;      // per-quad 128 x 64 (16 KB each)
        const int band = z >> 2, cg = z & 3;
        const long m0e = (long)bq * 2048 + band * 128;    // rows in preC/o_pre space
        const long n0e = cg * 512 + (long)qd * 128;
        const int wm = (wq >> 1) * 64, wn = (wq & 1) * 64;
        const int rl = lane >> 3, cl = (lane & 7) * 8;
        f32x4 acc[4][4] = {};
        for (int k0 = 0; k0 < 4096; k0 += 64) {
            __syncthreads();
            gld_lds16(preC + (m0e + 8 * wv + rl) * 4096 + cl + k0, &lA[wv * 512]);
#pragma unroll
            for (int i = 0; i < 4; ++i) {
                const int ci = wq * 4 + i;
                gld_lds16(wpre + (n0e + 8 * ci + rl) * 4096 + cl + k0, &lB[ci * 512]);
            }
            __syncthreads();
#pragma unroll
            for (int kk = 0; kk < 64; kk += 32) {
                bf16x8 av[4], bv[4];
#pragma unroll
                for (int i = 0; i < 4; ++i) {
                    av[i] = *(const bf16x8*)&lA[(wm + i * 16 + r) * 64 + kk + gg * 8];
                    bv[i] = *(const bf16x8*)&lB[(wn + i * 16 + r) * 64 + kk + gg * 8];
                }
#pragma unroll
                for (int mi = 0; mi < 4; ++mi)
#pragma unroll
                    for (int ni = 0; ni < 4; ++ni)
                        acc[mi][ni] = __builtin_amdgcn_mfma_f32_16x16x32_bf16(av[mi], bv[ni], acc[mi][ni], 0, 0, 0);
            }
        }
#pragma unroll
        for (int mi = 0; mi < 4; ++mi) {
#pragma unroll
            for (int ni = 0; ni < 4; ++ni) {
                const long col = n0e + wn + ni * 16 + r;
#pragma unroll
                for (int rr = 0; rr < 4; ++rr)
                    o_pre[(m0e + wm + mi * 16 + gg * 4 + rr) * 2048 + col] = acc[mi][ni][rr];
            }
        }
    }
}

// ---------- host ----------
extern "C" void kernel_launch(void* const* d_in, const int* in_sizes, int n_in,
                              void* d_out, int out_size, void* d_ws, size_t ws_size,
                              hipStream_t stream) {
    const float* te  = (const float*)d_in[0];
    const float* eh  = (const float*)d_in[1];
    const float* ef  = (const float*)d_in[2];
    const float* Wb  = (const float*)d_in[5];
    const float* bb  = (const float*)d_in[6];
    const float* Wk  = (const float*)d_in[7];
    const float* Wq  = (const float*)d_in[8];
    const float* We  = (const float*)d_in[9];
    const float* Wih = (const float*)d_in[10];
    const float* Whh = (const float*)d_in[11];
    const float* bih = (const float*)d_in[12];
    const float* bhh = (const float*)d_in[13];
    const float* Wpre= (const float*)d_in[14];

    char* ws = (char*)d_ws;
    if (ws_size < 272236544UL) return;   // loud failure (output stays poisoned)
    float*          h0f   = (float*)(ws + 0);                  // 64*1024*4
    float*          hp    = (float*)(ws + 262144);             // 64*4096*4
    unsigned short* hbf   = (unsigned short*)(ws + 1310720);   // 64*1024*2 (h0 only)
    unsigned short* efb   = (unsigned short*)(ws + 1441792);   // 64*2048*2 (init only)
    int*            syncb = (int*)(ws + 1441792 + 65536);      // per-bq barriers + batch counters
    float*          scb   = (float*)(ws + 1572864);            // 64*128*4 score exchange
    unsigned short* ehb   = (unsigned short*)(ws + 1703936);   // B*S*2048*2
    unsigned short* pkb   = (unsigned short*)(ws + 35258368);  // B*S*1024*2
    unsigned short* preC  = (unsigned short*)(ws + 52035584);  // B*T*4096*2
    float*          gix   = (float*)(ws + 119144448);          // B*T*3072*4
    unsigned short* wbb   = (unsigned short*)(ws + 219807744); // 1024*2048*2
    unsigned short* wkb   = (unsigned short*)(ws + 224002048); // 1024*2048*2
    unsigned short* whpb  = (unsigned short*)(ws + 228196352); // 4096*1024*2  [Wq; Whh]
    unsigned short* wihb  = (unsigned short*)(ws + 236584960); // 3072*3072*2
    unsigned short* wpreb = (unsigned short*)(ws + 255459328); // 2048*4096*2

    float* o_states = (float*)d_out;                 // (B,T,H)
    float* o_hf     = o_states + (long)B_ * T_ * H_; // (1,B,H)
    float* o_pre    = o_hf + (long)B_ * H_;          // (B,T,2H)

    auto cvt = [&](const float* s, unsigned short* d, long n) {
        k_cvt<<<dim3((unsigned)((n / 4 + 255) / 256)), 256, 0, stream>>>(s, d, n);
    };
    cvt(eh,  ehb,  (long)B_ * S_ * 2048);
    cvt(ef,  efb,  (long)B_ * 2048);
    cvt(Wb,  wbb,  1024L * 2048);
    cvt(Wk,  wkb,  1024L * 2048);
    cvt(Wq,  whpb, 1024L * 1024);
    cvt(Whh, whpb + 1024L * 1024, 3072L * 1024);
    cvt(Wih, wihb, 3072L * 3072);
    cvt(Wpre,wpreb,2048L * 4096);
    k_cvt_te<<<8192, 256, 0, stream>>>(te, preC, (long)B_ * T_ * 1024);

    // h0 = tanh(encoder_final @ W_bridge^T + b_bridge)  (consumes efb; hp = scratch)
    k_gemm<0><<<dim3(16, 1), 256, 0, stream>>>(efb, 2048, wbb, 2048, hp, 1024, 2048);
    k_h0act<<<256, 256, 0, stream>>>(hp, bb, h0f, hbf);
    // reset barrier vars + per-batch counters (stream-ordered, deterministic per call)
    (void)hipMemsetAsync(syncb, 0, 65536, stream);
    // proj_key = encoder_hidden @ W_key^T  (bf16 out): M=8192, N=1024, K=2048
    k_gemm128<1><<<dim3(8, 64), 256, 0, stream>>>(ehb, 2048, wkb, 2048, pkb, 1024, 2048);
    // gi_x = trg_embed @ W_ih[:, :E]^T  (f32 out): M=8192, N=3072, K=1024
    k_gemm128<0><<<dim3(24, 64), 256, 0, stream>>>(preC, 4096, wihb, 3072, gix, 3072, 1024);

    // persistent step loop + fused o_pre epilogue: 4 independent bq pipelines
    k_steps<<<NBLK, 1024, 0, stream>>>(pkb, ehb, whpb, wihb, We, gix, bih, bhh,
                                       h0f, hbf, hp, preC, wpreb, o_pre,
                                       o_states, o_hf, syncb, scb);
}